// Round 5
// baseline (516.124 us; speedup 1.0000x reference)
//
#include <hip/hip_runtime.h>
#include <hip/hip_bf16.h>

// GCN_71451075936314 on gfx950.
// R14: two latency cuts on R13 (which passed: lstm 211->177, VGPR 64, no
//      spill, occupancy 41% grid-limited at 782 blocks ~= 3/CU).
//      (a) lstm gx PREFETCH: gather x-gates for step t+1 during step t into
//          the alternate named reg set (gxA/gxB, 2-step-unrolled loop ->
//          static reg indexing). Removes the ~500-900cyc L3/HBM gather
//          stall from the barrier-to-barrier chain (R9's xstage trick,
//          dropped in R12/R13).
//      (b) featB deleted: ggemm converts f32 feature in-register (same
//          f2bf rounding, bit-identical); prep is now weights-only.
//          Saves ~38MB of HBM traffic + shortens prep.

#define NN     50000
#define HIDD   128
#define MAXD   16
#define NGRAPH 50
#define NCLSS  10
#define GRUH   32

typedef __attribute__((ext_vector_type(8))) short s16x8;    // 8 bf16 (4 VGPRs)
typedef __attribute__((ext_vector_type(4))) float f32x4;
typedef __hip_bfloat16 bf16;

#define MFMA16(a,b,c)  __builtin_amdgcn_mfma_f32_16x16x32_bf16((a),(b),(c),0,0,0)

__device__ __forceinline__ float bf2f(bf16 x) { return __bfloat162float(x); }
__device__ __forceinline__ bf16  f2bf(float x) { return __float2bfloat16(x); }
__device__ __forceinline__ s16x8 ldfrag(const bf16* p) { return *(const s16x8*)p; }

__device__ __forceinline__ s16x8 ldfrag_f32(const float* p) {
  const float4 a = *(const float4*)p;
  const float4 b = *(const float4*)(p + 4);
  union { s16x8 v; bf16 h[8]; } r;
  r.h[0] = f2bf(a.x); r.h[1] = f2bf(a.y); r.h[2] = f2bf(a.z); r.h[3] = f2bf(a.w);
  r.h[4] = f2bf(b.x); r.h[5] = f2bf(b.y); r.h[6] = f2bf(b.z); r.h[7] = f2bf(b.w);
  return r.v;
}

__device__ __forceinline__ float sigf(float x) {
  return __builtin_amdgcn_rcpf(1.0f + __expf(-x));
}
__device__ __forceinline__ float tanhf_(float x) {
  return 1.0f - 2.0f * __builtin_amdgcn_rcpf(1.0f + __expf(2.0f * x));
}

__device__ __forceinline__ unsigned packbf2(float a, float b) {
  union { bf16 h; unsigned short u; } x, y;
  x.h = f2bf(a); y.h = f2bf(b);
  return (unsigned)x.u | ((unsigned)y.u << 16);
}
__device__ __forceinline__ float lo2f(unsigned u) { return __uint_as_float(u << 16); }
__device__ __forceinline__ float hi2f(unsigned u) { return __uint_as_float(u & 0xffff0000u); }

// barrier that drains LDS ops only — global loads stay in flight
__device__ __forceinline__ void lgkm_barrier() {
  asm volatile("s_waitcnt lgkmcnt(0)\n\ts_barrier" ::: "memory");
}

// ---------------- prep: weight bf16 casts + transposes + bias fold ----------------
__global__ __launch_bounds__(256) void prep_kernel(const float* __restrict__ Wih,
                            const float* __restrict__ Whh, const float* __restrict__ bih,
                            const float* __restrict__ bhh, const float* __restrict__ Wself,
                            const float* __restrict__ Wneigh, const float* __restrict__ Wgc,
                            const float* __restrict__ Wgru,
                            bf16* WihB, bf16* WhhB, bf16* WsT, bf16* WnT,
                            bf16* WgT, bf16* WgruB, float* biasS) {
  const int total = 2 * 65536 + 3 * 16384 + 12288 + 512;   // 193024
  int stride = gridDim.x * blockDim.x;
  for (int idx = blockIdx.x * blockDim.x + threadIdx.x; idx < total; idx += stride) {
    int j = idx;
    if (j < 65536) { WihB[j] = f2bf(Wih[j]); continue; }
    j -= 65536;
    if (j < 65536) { WhhB[j] = f2bf(Whh[j]); continue; }
    j -= 65536;
    if (j < 16384) { int c = j >> 7, k = j & 127; WsT[j] = f2bf(Wself[k * HIDD + c]); continue; }
    j -= 16384;
    if (j < 16384) { int c = j >> 7, k = j & 127; WnT[j] = f2bf(Wneigh[k * HIDD + c]); continue; }
    j -= 16384;
    if (j < 16384) { int c = j >> 7, k = j & 127; WgT[j] = f2bf(Wgc[k * HIDD + c]); continue; }
    j -= 16384;
    if (j < 12288) { WgruB[j] = f2bf(Wgru[j]); continue; }
    j -= 12288;
    biasS[j] = bih[j] + bhh[j];
  }
}

// ---------------- counting sort by degree (DESCENDING): LDS hist ----------------
__global__ __launch_bounds__(256) void hist_kernel(const int* __restrict__ deg, int* hist) {
  __shared__ int lh[17];
  const int tid = threadIdx.x;
  if (tid < 17) lh[tid] = 0;
  __syncthreads();
  const int i = blockIdx.x * 256 + tid;
  if (i < NN) atomicAdd(&lh[deg[i]], 1);
  __syncthreads();
  if (tid < 17 && lh[tid]) atomicAdd(&hist[tid], lh[tid]);
}

__global__ __launch_bounds__(256) void scatter_kernel(const int* __restrict__ deg,
                                                      const int* __restrict__ hist,
                                                      int* __restrict__ resv,
                                                      int* __restrict__ perm) {
  __shared__ int lh[17], lbase[17], lpos[17];
  const int tid = threadIdx.x;
  if (tid < 17) { lh[tid] = 0; lpos[tid] = 0; }
  __syncthreads();
  const int i = blockIdx.x * 256 + tid;
  const int d = (i < NN) ? deg[i] : -1;
  if (d >= 0) atomicAdd(&lh[d], 1);
  __syncthreads();
  if (tid < 17) {
    int pre = 0;
    for (int k = tid + 1; k < 17; ++k) pre += hist[k];   // descending: larger degs first
    lbase[tid] = pre + (lh[tid] ? atomicAdd(&resv[tid], lh[tid]) : 0);
  }
  __syncthreads();
  if (d >= 0) {
    const int p = lbase[d] + atomicAdd(&lpos[d], 1);
    perm[p] = i;
  }
}

// ---------------- G-GEMM: G'[n][hcol*4+gate] = feat[n] @ Wih^T + bias ----------------
// Reads FLOAT feature directly (in-register f2bf, bit-identical to featB).
// Transposed-C MFMA with packed vrows (vrow = hl*4 + gate): lane's f32x4 =
// 4 gates of one hcol -> one 8B bf16x4 store, gate-packed for lstm gathers.
__global__ __launch_bounds__(256) void ggemm_kernel(const float* __restrict__ featF,
                                                    const bf16* __restrict__ WihB,
                                                    const float* __restrict__ biasS,
                                                    bf16* __restrict__ Gp) {
  const int lane = threadIdx.x & 63, wave = threadIdx.x >> 6;
  const int l15 = lane & 15, quad = lane >> 4;
  const int nb = blockIdx.x * 64;

  // x B-frags: 64 rows of feature, 16 per l15-slot x 4 nt, k-chunk by quad
  s16x8 Bx[4][4];
#pragma unroll
  for (int nt = 0; nt < 4; ++nt) {
    int arow = nb + nt * 16 + l15; if (arow >= NN) arow = NN - 1;
#pragma unroll
    for (int kt = 0; kt < 4; ++kt)
      Bx[nt][kt] = ldfrag_f32(featF + (size_t)arow * HIDD + kt * 32 + quad * 8);
  }

  for (int hg = wave * 8; hg < wave * 8 + 8; ++hg) {
    // A-frags: Wih packed vrows: row = (l15&3)*128 + hg*4 + (l15>>2)
    const int wr = (l15 & 3) * HIDD + hg * 4 + (l15 >> 2);
    s16x8 Aw[4];
#pragma unroll
    for (int kt = 0; kt < 4; ++kt)
      Aw[kt] = ldfrag(WihB + (size_t)wr * HIDD + kt * 32 + quad * 8);
    const int hcol = hg * 4 + quad;
    float b0 = biasS[0 * HIDD + hcol], b1 = biasS[1 * HIDD + hcol];
    float b2 = biasS[2 * HIDD + hcol], b3 = biasS[3 * HIDD + hcol];
#pragma unroll
    for (int nt = 0; nt < 4; ++nt) {
      f32x4 acc = {0.f, 0.f, 0.f, 0.f};
#pragma unroll
      for (int kt = 0; kt < 4; ++kt)
        acc = MFMA16(Aw[kt], Bx[nt][kt], acc);
      const int node = nb + nt * 16 + l15;
      if (node < NN) {
        unsigned u0 = packbf2(acc[0] + b0, acc[1] + b1);
        unsigned u1 = packbf2(acc[2] + b2, acc[3] + b3);
        *(uint2*)(Gp + (size_t)node * 512 + hcol * 4) = make_uint2(u0, u1);
      }
    }
  }
}

// ---------------- LSTM recurrence: 1024 thr / 16 waves / 64 nodes ----------------
// h-part only (x-gates gathered from G' with one-step prefetch). Transposed-C
// MFMA, packed vrows: wave w owns hcols [w*8, w*8+8) as 2 gt-tiles.
// Lane (l15,quad) acc[gt][nt] f32x4 = gates i,f,g,o of cell
// (node nt*16+l15, hcol w*8+gt*4+quad). Whh pinned 32 VGPR. ~3 blocks/CU.
__global__ __launch_bounds__(1024, 4) void lstm_kernel(const bf16* __restrict__ Gp,
                                                       const bf16* __restrict__ WhhB,
                                                       const int* __restrict__ nbr_idx,
                                                       const int* __restrict__ deg,
                                                       const int* __restrict__ perm,
                                                       bf16* __restrict__ hTB) {
  __shared__ __align__(16) bf16 Hs[2][64 * 128];  // 32KB: h dbuf, oct-xor swizzled
  __shared__ int nbr_s[16 * 64];                  // [t][row]
  __shared__ int nodes_s[64];
  __shared__ int degs_s[64];

  const int tid = threadIdx.x;
  const int lane = tid & 63, w = tid >> 6;        // w = hcol-block 0..15
  const int l15 = lane & 15, quad = lane >> 4;
  const int base = blockIdx.x * 64;

  if (tid < 64) {
    const int gi = base + tid;
    const int nd = (gi < NN) ? perm[gi] : -1;
    nodes_s[tid] = nd;
    degs_s[tid] = (nd >= 0) ? deg[nd] : 0;
  }
  __syncthreads();
  {
    const int row = tid & 63, t = tid >> 6;       // exactly one entry per thread
    const int nd = nodes_s[row];
    nbr_s[t * 64 + row] = (nd >= 0) ? nbr_idx[nd * MAXD + t] : 0;
  }

  // pinned Whh packed frags: vrow v=l15 -> Whh row (v&3)*128 + w*8 + gt*4 + (v>>2)
  s16x8 Bh[2][4];
#pragma unroll
  for (int gt = 0; gt < 2; ++gt) {
    const int wr = (l15 & 3) * HIDD + w * 8 + gt * 4 + (l15 >> 2);
#pragma unroll
    for (int kt = 0; kt < 4; ++kt) {
      Bh[gt][kt] = ldfrag(WhhB + (size_t)wr * HIDD + kt * 32 + quad * 8);
      asm volatile("" : "+v"(Bh[gt][kt]));
    }
  }

  __syncthreads();                                // nbr_s visible
  const int maxdeg = degs_s[0];                   // descending sort -> block max

  int mydeg[4];
#pragma unroll
  for (int nt = 0; nt < 4; ++nt) mydeg[nt] = degs_s[nt * 16 + l15];

  // per-thread G' element offsets (col base = (w*8+gt*4+quad)*4)
  const int gofs0 = (w * 8 + 0 * 4 + quad) * 4;
  const int gofs1 = (w * 8 + 1 * 4 + quad) * 4;

  float cst[2][4] = {{0.f, 0.f, 0.f, 0.f}, {0.f, 0.f, 0.f, 0.f}};
  float hprev[2][4] = {{0.f, 0.f, 0.f, 0.f}, {0.f, 0.f, 0.f, 0.f}};

  uint2 gxA[2][4], gxB[2][4];
  // prologue: gather x-gates for t=0 into gxA
#pragma unroll
  for (int nt = 0; nt < 4; ++nt) {
    const int nb1 = nbr_s[0 * 64 + nt * 16 + l15];
    const bf16* gr = Gp + (size_t)nb1 * 512;
    gxA[0][nt] = *(const uint2*)(gr + gofs0);
    gxA[1][nt] = *(const uint2*)(gr + gofs1);
  }

  // one step: consume GXU (loaded a full step ago), prefetch t+1 into GXP
  auto step = [&](int T, uint2 (&GXU)[2][4], uint2 (&GXP)[2][4]) {
    const int cur = T & 1, nxt = cur ^ 1;
    // issue next step's gathers early (vmcnt-waited next step; covered)
    const int tn = (T + 1 < maxdeg) ? (T + 1) : T;
#pragma unroll
    for (int nt = 0; nt < 4; ++nt) {
      const int nb1 = nbr_s[tn * 64 + nt * 16 + l15];
      const bf16* gr = Gp + (size_t)nb1 * 512;
      GXP[0][nt] = *(const uint2*)(gr + gofs0);
      GXP[1][nt] = *(const uint2*)(gr + gofs1);
    }

    f32x4 acc[2][4];
#pragma unroll
    for (int gt = 0; gt < 2; ++gt)
#pragma unroll
      for (int nt = 0; nt < 4; ++nt) acc[gt][nt] = (f32x4){0.f, 0.f, 0.f, 0.f};

    // h-part: gates += Whh_packed @ h^T  (skip at t=0: h0 = 0)
    if (T > 0) {
#pragma unroll
      for (int kt = 0; kt < 4; ++kt) {
#pragma unroll
        for (int nt = 0; nt < 4; ++nt) {
          const int row = nt * 16 + l15;
          const s16x8 ah = ldfrag(Hs[cur] + row * 128 + (((kt * 4 + quad) ^ l15) * 8));
#pragma unroll
          for (int gt = 0; gt < 2; ++gt)
            acc[gt][nt] = MFMA16(Bh[gt][kt], ah, acc[gt][nt]);
        }
      }
    }

    // elementwise cell: lane's f32x4 = all 4 gates of one cell
#pragma unroll
    for (int gt = 0; gt < 2; ++gt) {
      const int col = w * 8 + gt * 4 + quad;
#pragma unroll
      for (int nt = 0; nt < 4; ++nt) {
        const int row = nt * 16 + l15;
        const uint2 g = GXU[gt][nt];
        const float g_i = acc[gt][nt][0] + lo2f(g.x);
        const float g_f = acc[gt][nt][1] + hi2f(g.x);
        const float g_g = acc[gt][nt][2] + lo2f(g.y);
        const float g_o = acc[gt][nt][3] + hi2f(g.y);
        const float iv = sigf(g_i), fv = sigf(g_f);
        const float gv = tanhf_(g_g), ov = sigf(g_o);
        const float cn = fv * cst[gt][nt] + iv * gv;
        const float hn_new = ov * tanhf_(cn);
        const bool act = (T < mydeg[nt]);
        if (act) cst[gt][nt] = cn;
        const float hn = act ? hn_new : hprev[gt][nt];
        hprev[gt][nt] = hn;
        Hs[nxt][row * 128 + ((w ^ (row & 15)) * 8) + (col & 7)] = f2bf(hn);
      }
    }
    lgkm_barrier();   // single barrier: dbuf writes visible, reads done
  };

  for (int t = 0; t < maxdeg; t += 2) {
    step(t, gxA, gxB);
    if (t + 1 < maxdeg) step(t + 1, gxB, gxA);   // uniform cond: barrier-safe
  }

  // epilogue: Hs[maxdeg&1] (swizzled) -> hTB
  const bf16* Hf = Hs[maxdeg & 1];
  {
    const int row = tid >> 4, j = tid & 15;       // 64 rows x 16 octs, one per thread
    const int nd = nodes_s[row];
    if (nd >= 0) {
      const s16x8 v = ldfrag(Hf + row * 128 + ((j ^ (row & 15)) * 8));
      *(s16x8*)(hTB + (size_t)nd * HIDD + j * 8) = v;
    }
  }
}

// ------- SAGE: h1n = relu(feat@W_self + hT@W_neigh + b) * rsqrt(deg) -------
// feat read from the ORIGINAL float input; inline f2bf = bit-identical frags.
__global__ __launch_bounds__(256) void sage_kernel(const float* __restrict__ featF,
                                                   const bf16* __restrict__ hTB,
                                                   const bf16* __restrict__ WsT,
                                                   const bf16* __restrict__ WnT,
                                                   const float* __restrict__ b_sage,
                                                   const int* __restrict__ deg,
                                                   bf16* __restrict__ h1n) {
  const int lane = threadIdx.x & 63, wave = threadIdx.x >> 6;
  const int l15 = lane & 15, quad = lane >> 4;
  const int nb = blockIdx.x * 64 + wave * 16;
  int arow = nb + l15; if (arow >= NN) arow = NN - 1;
  s16x8 Fa[4], Ha[4];
#pragma unroll
  for (int kt = 0; kt < 4; ++kt) {
    Fa[kt] = ldfrag_f32(featF + (size_t)arow * HIDD + kt * 32 + quad * 8);
    Ha[kt] = ldfrag(hTB + (size_t)arow * HIDD + kt * 32 + quad * 8);
  }
  int nodes[4]; float nrm[4];
#pragma unroll
  for (int r = 0; r < 4; ++r) {
    const int nd = nb + quad * 4 + r;
    nodes[r] = nd;
    nrm[r] = rsqrtf((float)deg[(nd < NN) ? nd : (NN - 1)]);
  }
  for (int ct = 0; ct < 8; ++ct) {
    const int col = ct * 16 + l15;
    f32x4 acc = {0.f, 0.f, 0.f, 0.f};
#pragma unroll
    for (int kt = 0; kt < 4; ++kt) {
      acc = MFMA16(Fa[kt], ldfrag(WsT + col * HIDD + kt * 32 + quad * 8), acc);
      acc = MFMA16(Ha[kt], ldfrag(WnT + col * HIDD + kt * 32 + quad * 8), acc);
    }
    const float bb = b_sage[col];
#pragma unroll
    for (int r = 0; r < 4; ++r)
      if (nodes[r] < NN) {
        const float v = fmaxf(acc[r] + bb, 0.f) * nrm[r];
        h1n[(size_t)nodes[r] * HIDD + col] = f2bf(v);
      }
  }
}

// ------- GraphConv aggregate: agg[n] = rsqrt(deg[n]) * sum_{t<deg} h1n[nbr[n,t]] -------
__global__ __launch_bounds__(256) void agg_kernel(const bf16* __restrict__ h1n,
                                                  const int* __restrict__ nbr_idx,
                                                  const int* __restrict__ deg,
                                                  bf16* __restrict__ aggB) {
  const int wave = threadIdx.x >> 6, lane = threadIdx.x & 63;
  const int node = blockIdx.x * 4 + wave;
  if (node >= NN) return;
  const int d = deg[node];
  const int idx_l = nbr_idx[node * MAXD + (lane & 15)];   // coalesced, broadcast via shfl
  const int c = lane * 2;
  float a0 = 0.f, a1 = 0.f;
  for (int t = 0; t < d; ++t) {
    const int nbr = __shfl(idx_l, t, 64);
    const __hip_bfloat162 v = *(const __hip_bfloat162*)(h1n + (size_t)nbr * HIDD + c);
    a0 += __bfloat162float(v.x);
    a1 += __bfloat162float(v.y);
  }
  const float nm = rsqrtf((float)d);
  aggB[(size_t)node * HIDD + c]     = f2bf(a0 * nm);
  aggB[(size_t)node * HIDD + c + 1] = f2bf(a1 * nm);
}

// ------- fused GraphConv GEMM + GRU: gout = gru(relu(agg @ W_gc + b_gc)) -------
__global__ __launch_bounds__(256) void gcgru_kernel(const bf16* __restrict__ aggB,
                                                    const bf16* __restrict__ WgT,
                                                    const float* __restrict__ b_gc,
                                                    const bf16* __restrict__ WgruB,
                                                    const float* __restrict__ bih,
                                                    const float* __restrict__ bhh,
                                                    float* __restrict__ gout) {
  __shared__ __align__(16) bf16 H2[64 * 136];     // h2 tile, padded pitch
  const int lane = threadIdx.x & 63, wave = threadIdx.x >> 6;
  const int l15 = lane & 15, quad = lane >> 4;
  const int nb = blockIdx.x * 64 + wave * 16;
  int arow = nb + l15; if (arow >= NN) arow = NN - 1;
  s16x8 A[4];
#pragma unroll
  for (int kt = 0; kt < 4; ++kt) A[kt] = ldfrag(aggB + (size_t)arow * HIDD + kt * 32 + quad * 8);
  // gc: h2 = relu(agg @ W_gc + b) -> LDS (C-layout -> row-major for gru A)
  for (int ct = 0; ct < 8; ++ct) {
    const int col = ct * 16 + l15;
    f32x4 acc = {0.f, 0.f, 0.f, 0.f};
#pragma unroll
    for (int kt = 0; kt < 4; ++kt)
      acc = MFMA16(A[kt], ldfrag(WgT + col * HIDD + kt * 32 + quad * 8), acc);
    const float bb = b_gc[col];
#pragma unroll
    for (int r = 0; r < 4; ++r)
      H2[(wave * 16 + quad * 4 + r) * 136 + col] = f2bf(fmaxf(acc[r] + bb, 0.f));
  }
  __syncthreads();
  // gru over rows wave*16 + l15
  s16x8 A2[4];
#pragma unroll
  for (int kt = 0; kt < 4; ++kt)
    A2[kt] = ldfrag(H2 + (wave * 16 + l15) * 136 + kt * 32 + quad * 8);
  f32x4 acc[6];
#pragma unroll
  for (int ct = 0; ct < 6; ++ct) {
    f32x4 a = {0.f, 0.f, 0.f, 0.f};
#pragma unroll
    for (int kt = 0; kt < 4; ++kt)
      a = MFMA16(A2[kt], ldfrag(WgruB + (ct * 16 + l15) * HIDD + kt * 32 + quad * 8), a);
    acc[ct] = a;
  }
#pragma unroll
  for (int u = 0; u < 2; ++u) {
    const int cu = 16 * u + l15;
    const float br = bih[cu] + bhh[cu];
    const float bz = bih[32 + cu] + bhh[32 + cu];
    const float bni = bih[64 + cu];
    const float bnh = bhh[64 + cu];
#pragma unroll
    for (int r = 0; r < 4; ++r) {
      const int node = nb + quad * 4 + r;
      if (node < NN) {
        const float rv = sigf(acc[u][r] + br);
        const float zv = sigf(acc[2 + u][r] + bz);
        const float nv = tanhf_(acc[4 + u][r] + bni + rv * bnh);
        gout[(size_t)node * GRUH + cu] = (1.f - zv) * nv;
      }
    }
  }
}

// ------- two-phase per-graph mean pool + classifier -------
#define POOL_CHUNK 512
__global__ __launch_bounds__(256) void pool_partial_kernel(const float* __restrict__ gout,
                                                           const int* __restrict__ gids,
                                                           float* __restrict__ sums,
                                                           float* __restrict__ cnts) {
  __shared__ float ls[NGRAPH * GRUH];
  __shared__ float lc[NGRAPH];
  const int tid = threadIdx.x;
  for (int i = tid; i < NGRAPH * GRUH; i += 256) ls[i] = 0.f;
  if (tid < NGRAPH) lc[tid] = 0.f;
  __syncthreads();

  const int wave = tid >> 6, lane = tid & 63;
  const int c = lane & 31, half = lane >> 5;
  const int base = blockIdx.x * POOL_CHUNK + wave * (POOL_CHUNK / 8);

  float accv = 0.f, ccnt = 0.f;
  int curg = -1;
  for (int it = 0; it < POOL_CHUNK / 16; ++it) {
    const int n = base + it * 2 + half;
    if (n < NN) {
      const int g = gids[n];
      const float v = gout[(size_t)n * GRUH + c];
      if (g != curg) {
        if (curg >= 0) {
          atomicAdd(&ls[curg * GRUH + c], accv);
          if (c == 0) atomicAdd(&lc[curg], ccnt);
        }
        curg = g; accv = 0.f; ccnt = 0.f;
      }
      accv += v; ccnt += 1.f;
    }
  }
  if (curg >= 0) {
    atomicAdd(&ls[curg * GRUH + c], accv);
    if (c == 0) atomicAdd(&lc[curg], ccnt);
  }
  __syncthreads();
  for (int i = tid; i < NGRAPH * GRUH; i += 256)
    if (ls[i] != 0.f) atomicAdd(&sums[i], ls[i]);
  if (tid < NGRAPH && lc[tid] != 0.f) atomicAdd(&cnts[tid], lc[tid]);
}

__global__ __launch_bounds__(256) void pool_final_kernel(const float* __restrict__ sums,
                                                         const float* __restrict__ cnts,
                                                         const float* __restrict__ Wcls,
                                                         const float* __restrict__ bcls,
                                                         float* __restrict__ out) {
  const int idx = blockIdx.x * blockDim.x + threadIdx.x;
  if (idx >= NGRAPH * NCLSS) return;
  const int g = idx / NCLSS, k = idx % NCLSS;
  const float inv = 1.0f / cnts[g];
  float acc = bcls[k];
#pragma unroll
  for (int cc = 0; cc < GRUH; ++cc)
    acc += sums[g * GRUH + cc] * inv * Wcls[cc * NCLSS + k];
  out[idx] = acc;
}

extern "C" void kernel_launch(void* const* d_in, const int* in_sizes, int n_in,
                              void* d_out, int out_size, void* d_ws, size_t ws_size,
                              hipStream_t stream) {
  const float* feature  = (const float*)d_in[0];
  const int*   nbr_idx  = (const int*)d_in[1];
  const int*   deg      = (const int*)d_in[2];
  const int*   gids     = (const int*)d_in[3];
  const float* lstm_Wih = (const float*)d_in[4];
  const float* lstm_Whh = (const float*)d_in[5];
  const float* lstm_bih = (const float*)d_in[6];
  const float* lstm_bhh = (const float*)d_in[7];
  const float* W_self   = (const float*)d_in[8];
  const float* W_neigh  = (const float*)d_in[9];
  const float* b_sage   = (const float*)d_in[10];
  const float* W_gc     = (const float*)d_in[11];
  const float* b_gc     = (const float*)d_in[12];
  const float* Wih_gru  = (const float*)d_in[13];
  const float* bih_gru  = (const float*)d_in[14];
  const float* bhh_gru  = (const float*)d_in[15];
  const float* W_cls    = (const float*)d_in[16];
  const float* b_cls    = (const float*)d_in[17];

  // workspace: peak 64.8 MB (within the 65.4 MB proven bound).
  // Timeline aliases: hTB at 0 (lstm out, sage in), gout aliases it after
  // sage; Gp dead after lstm -> h1nB/aggB inside its region.
  char* ws = (char*)d_ws;
  bf16*  hTB   = (bf16*)(ws + 0);           // [NN,128] 12.8MB
  float* gout  = (float*)(ws + 0);          // alias hTB (gcgru out, 6.4MB)
  bf16*  Gp    = (bf16*)(ws + 12800000);    // [NN,512] 51.2MB (dead after lstm)
  bf16*  h1nB  = (bf16*)(ws + 12800000);    // alias Gp[0:12.8M] (sage out, agg in)
  bf16*  aggB  = (bf16*)(ws + 25600000);    // alias Gp[12.8:25.6M] (agg out, gcgru in)
  const size_t wo = 64000000;
  bf16*  WihB  = (bf16*)(ws + wo);
  bf16*  WhhB  = (bf16*)(ws + wo + 131072);
  bf16*  WsT   = (bf16*)(ws + wo + 262144);
  bf16*  WnT   = (bf16*)(ws + wo + 294912);
  bf16*  WgT   = (bf16*)(ws + wo + 327680);
  bf16*  WgruB = (bf16*)(ws + wo + 360448);
  float* biasS = (float*)(ws + wo + 385024);
  int*   perm  = (int*)(ws + 64500000);
  int*   hist  = (int*)(ws + 64800000);     // [17]
  int*   resv  = hist + 17;                 // [17]
  float* psums = (float*)(ws + 64801216);   // [50][32]
  float* pcnts = psums + NGRAPH * GRUH;     // [50]

  prep_kernel<<<754, 256, 0, stream>>>(lstm_Wih, lstm_Whh, lstm_bih, lstm_bhh,
                                       W_self, W_neigh, W_gc, Wih_gru,
                                       WihB, WhhB, WsT, WnT, WgT, WgruB, biasS);
  hipMemsetAsync(hist, 0, 34 * sizeof(int), stream);
  hipMemsetAsync(psums, 0, (NGRAPH * GRUH + NGRAPH) * sizeof(float), stream);
  hist_kernel<<<196, 256, 0, stream>>>(deg, hist);
  scatter_kernel<<<196, 256, 0, stream>>>(deg, hist, resv, perm);
  ggemm_kernel<<<782, 256, 0, stream>>>(feature, WihB, biasS, Gp);
  lstm_kernel<<<782, 1024, 0, stream>>>(Gp, WhhB, nbr_idx, deg, perm, hTB);
  sage_kernel<<<782, 256, 0, stream>>>(feature, hTB, WsT, WnT, b_sage, deg, h1nB);
  agg_kernel<<<12500, 256, 0, stream>>>(h1nB, nbr_idx, deg, aggB);
  gcgru_kernel<<<782, 256, 0, stream>>>(aggB, WgT, b_gc, WgruB, bih_gru, bhh_gru, gout);
  pool_partial_kernel<<<(NN + POOL_CHUNK - 1) / POOL_CHUNK, 256, 0, stream>>>(gout, gids, psums, pcnts);
  pool_final_kernel<<<2, 256, 0, stream>>>(psums, pcnts, W_cls, b_cls, (float*)d_out);
}

// Round 7
// 479.842 us; speedup vs baseline: 1.0756x; 1.0756x over previous
//
#include <hip/hip_runtime.h>
#include <hip/hip_bf16.h>

// GCN_71451075936314 on gfx950.
// R16: same prefetch mechanism as R14/R15, plainest expression. R15
//      (macro 2-step unroll) hit "container failed twice" — semantically
//      identical to R14 which RAN, so suspect infra or toolchain, not
//      semantics. This version: single inline loop body + register
//      rotation (gxA consumed, gxB prefetched, gxA=gxB at step end; all
//      indices compile-time). No lambda (R14's scratch bug: WRITE 290MB),
//      no macro. Register budget: R13 measured 64 VGPR + 16 for gxB ~= 80
//      <= 128 cap of launch_bounds(1024,4).
//      Success: WRITE ~12.5MB, VGPR 80-96, lstm <= 165us.

#define NN     50000
#define HIDD   128
#define MAXD   16
#define NGRAPH 50
#define NCLSS  10
#define GRUH   32

typedef __attribute__((ext_vector_type(8))) short s16x8;    // 8 bf16 (4 VGPRs)
typedef __attribute__((ext_vector_type(4))) float f32x4;
typedef __hip_bfloat16 bf16;

#define MFMA16(a,b,c)  __builtin_amdgcn_mfma_f32_16x16x32_bf16((a),(b),(c),0,0,0)

__device__ __forceinline__ float bf2f(bf16 x) { return __bfloat162float(x); }
__device__ __forceinline__ bf16  f2bf(float x) { return __float2bfloat16(x); }
__device__ __forceinline__ s16x8 ldfrag(const bf16* p) { return *(const s16x8*)p; }

__device__ __forceinline__ s16x8 ldfrag_f32(const float* p) {
  const float4 a = *(const float4*)p;
  const float4 b = *(const float4*)(p + 4);
  union { s16x8 v; bf16 h[8]; } r;
  r.h[0] = f2bf(a.x); r.h[1] = f2bf(a.y); r.h[2] = f2bf(a.z); r.h[3] = f2bf(a.w);
  r.h[4] = f2bf(b.x); r.h[5] = f2bf(b.y); r.h[6] = f2bf(b.z); r.h[7] = f2bf(b.w);
  return r.v;
}

__device__ __forceinline__ float sigf(float x) {
  return __builtin_amdgcn_rcpf(1.0f + __expf(-x));
}
__device__ __forceinline__ float tanhf_(float x) {
  return 1.0f - 2.0f * __builtin_amdgcn_rcpf(1.0f + __expf(2.0f * x));
}

__device__ __forceinline__ unsigned packbf2(float a, float b) {
  union { bf16 h; unsigned short u; } x, y;
  x.h = f2bf(a); y.h = f2bf(b);
  return (unsigned)x.u | ((unsigned)y.u << 16);
}
__device__ __forceinline__ float lo2f(unsigned u) { return __uint_as_float(u << 16); }
__device__ __forceinline__ float hi2f(unsigned u) { return __uint_as_float(u & 0xffff0000u); }

// barrier that drains LDS ops only — global loads stay in flight
__device__ __forceinline__ void lgkm_barrier() {
  asm volatile("s_waitcnt lgkmcnt(0)\n\ts_barrier" ::: "memory");
}

// ---------------- prep: weight bf16 casts + transposes + bias fold ----------------
__global__ __launch_bounds__(256) void prep_kernel(const float* __restrict__ Wih,
                            const float* __restrict__ Whh, const float* __restrict__ bih,
                            const float* __restrict__ bhh, const float* __restrict__ Wself,
                            const float* __restrict__ Wneigh, const float* __restrict__ Wgc,
                            const float* __restrict__ Wgru,
                            bf16* WihB, bf16* WhhB, bf16* WsT, bf16* WnT,
                            bf16* WgT, bf16* WgruB, float* biasS) {
  const int total = 2 * 65536 + 3 * 16384 + 12288 + 512;   // 193024
  int stride = gridDim.x * blockDim.x;
  for (int idx = blockIdx.x * blockDim.x + threadIdx.x; idx < total; idx += stride) {
    int j = idx;
    if (j < 65536) { WihB[j] = f2bf(Wih[j]); continue; }
    j -= 65536;
    if (j < 65536) { WhhB[j] = f2bf(Whh[j]); continue; }
    j -= 65536;
    if (j < 16384) { int c = j >> 7, k = j & 127; WsT[j] = f2bf(Wself[k * HIDD + c]); continue; }
    j -= 16384;
    if (j < 16384) { int c = j >> 7, k = j & 127; WnT[j] = f2bf(Wneigh[k * HIDD + c]); continue; }
    j -= 16384;
    if (j < 16384) { int c = j >> 7, k = j & 127; WgT[j] = f2bf(Wgc[k * HIDD + c]); continue; }
    j -= 16384;
    if (j < 12288) { WgruB[j] = f2bf(Wgru[j]); continue; }
    j -= 12288;
    biasS[j] = bih[j] + bhh[j];
  }
}

// ---------------- counting sort by degree (DESCENDING): LDS hist ----------------
__global__ __launch_bounds__(256) void hist_kernel(const int* __restrict__ deg, int* hist) {
  __shared__ int lh[17];
  const int tid = threadIdx.x;
  if (tid < 17) lh[tid] = 0;
  __syncthreads();
  const int i = blockIdx.x * 256 + tid;
  if (i < NN) atomicAdd(&lh[deg[i]], 1);
  __syncthreads();
  if (tid < 17 && lh[tid]) atomicAdd(&hist[tid], lh[tid]);
}

__global__ __launch_bounds__(256) void scatter_kernel(const int* __restrict__ deg,
                                                      const int* __restrict__ hist,
                                                      int* __restrict__ resv,
                                                      int* __restrict__ perm) {
  __shared__ int lh[17], lbase[17], lpos[17];
  const int tid = threadIdx.x;
  if (tid < 17) { lh[tid] = 0; lpos[tid] = 0; }
  __syncthreads();
  const int i = blockIdx.x * 256 + tid;
  const int d = (i < NN) ? deg[i] : -1;
  if (d >= 0) atomicAdd(&lh[d], 1);
  __syncthreads();
  if (tid < 17) {
    int pre = 0;
    for (int k = tid + 1; k < 17; ++k) pre += hist[k];   // descending: larger degs first
    lbase[tid] = pre + (lh[tid] ? atomicAdd(&resv[tid], lh[tid]) : 0);
  }
  __syncthreads();
  if (d >= 0) {
    const int p = lbase[d] + atomicAdd(&lpos[d], 1);
    perm[p] = i;
  }
}

// ---------------- G-GEMM: G'[n][hcol*4+gate] = feat[n] @ Wih^T + bias ----------------
// Reads FLOAT feature directly (in-register f2bf, bit-identical to featB).
// Transposed-C MFMA with packed vrows (vrow = hl*4 + gate): lane's f32x4 =
// 4 gates of one hcol -> one 8B bf16x4 store, gate-packed for lstm gathers.
__global__ __launch_bounds__(256) void ggemm_kernel(const float* __restrict__ featF,
                                                    const bf16* __restrict__ WihB,
                                                    const float* __restrict__ biasS,
                                                    bf16* __restrict__ Gp) {
  const int lane = threadIdx.x & 63, wave = threadIdx.x >> 6;
  const int l15 = lane & 15, quad = lane >> 4;
  const int nb = blockIdx.x * 64;

  // x B-frags: 64 rows of feature, 16 per l15-slot x 4 nt, k-chunk by quad
  s16x8 Bx[4][4];
#pragma unroll
  for (int nt = 0; nt < 4; ++nt) {
    int arow = nb + nt * 16 + l15; if (arow >= NN) arow = NN - 1;
#pragma unroll
    for (int kt = 0; kt < 4; ++kt)
      Bx[nt][kt] = ldfrag_f32(featF + (size_t)arow * HIDD + kt * 32 + quad * 8);
  }

  for (int hg = wave * 8; hg < wave * 8 + 8; ++hg) {
    // A-frags: Wih packed vrows: row = (l15&3)*128 + hg*4 + (l15>>2)
    const int wr = (l15 & 3) * HIDD + hg * 4 + (l15 >> 2);
    s16x8 Aw[4];
#pragma unroll
    for (int kt = 0; kt < 4; ++kt)
      Aw[kt] = ldfrag(WihB + (size_t)wr * HIDD + kt * 32 + quad * 8);
    const int hcol = hg * 4 + quad;
    float b0 = biasS[0 * HIDD + hcol], b1 = biasS[1 * HIDD + hcol];
    float b2 = biasS[2 * HIDD + hcol], b3 = biasS[3 * HIDD + hcol];
#pragma unroll
    for (int nt = 0; nt < 4; ++nt) {
      f32x4 acc = {0.f, 0.f, 0.f, 0.f};
#pragma unroll
      for (int kt = 0; kt < 4; ++kt)
        acc = MFMA16(Aw[kt], Bx[nt][kt], acc);
      const int node = nb + nt * 16 + l15;
      if (node < NN) {
        unsigned u0 = packbf2(acc[0] + b0, acc[1] + b1);
        unsigned u1 = packbf2(acc[2] + b2, acc[3] + b3);
        *(uint2*)(Gp + (size_t)node * 512 + hcol * 4) = make_uint2(u0, u1);
      }
    }
  }
}

// ---------------- LSTM recurrence: 1024 thr / 16 waves / 64 nodes ----------------
// h-part only; x-gates gathered from G' with one-step prefetch via register
// rotation (gxA consumed, gxB prefetched, gxA=gxB at step end — all static
// indices, single inline body). Transposed-C MFMA, packed vrows. Whh pinned.
__global__ __launch_bounds__(1024, 4) void lstm_kernel(const bf16* __restrict__ Gp,
                                                       const bf16* __restrict__ WhhB,
                                                       const int* __restrict__ nbr_idx,
                                                       const int* __restrict__ deg,
                                                       const int* __restrict__ perm,
                                                       bf16* __restrict__ hTB) {
  __shared__ __align__(16) bf16 Hs[2][64 * 128];  // 32KB: h dbuf, oct-xor swizzled
  __shared__ int nbr_s[16 * 64];                  // [t][row]
  __shared__ int nodes_s[64];
  __shared__ int degs_s[64];

  const int tid = threadIdx.x;
  const int lane = tid & 63, w = tid >> 6;        // w = hcol-block 0..15
  const int l15 = lane & 15, quad = lane >> 4;
  const int base = blockIdx.x * 64;

  if (tid < 64) {
    const int gi = base + tid;
    const int nd = (gi < NN) ? perm[gi] : -1;
    nodes_s[tid] = nd;
    degs_s[tid] = (nd >= 0) ? deg[nd] : 0;
  }
  __syncthreads();
  {
    const int row = tid & 63, t = tid >> 6;       // exactly one entry per thread
    const int nd = nodes_s[row];
    nbr_s[t * 64 + row] = (nd >= 0) ? nbr_idx[nd * MAXD + t] : 0;
  }

  // pinned Whh packed frags: vrow v=l15 -> Whh row (v&3)*128 + w*8 + gt*4 + (v>>2)
  s16x8 Bh[2][4];
#pragma unroll
  for (int gt = 0; gt < 2; ++gt) {
    const int wr = (l15 & 3) * HIDD + w * 8 + gt * 4 + (l15 >> 2);
#pragma unroll
    for (int kt = 0; kt < 4; ++kt) {
      Bh[gt][kt] = ldfrag(WhhB + (size_t)wr * HIDD + kt * 32 + quad * 8);
      asm volatile("" : "+v"(Bh[gt][kt]));
    }
  }

  __syncthreads();                                // nbr_s visible
  const int maxdeg = degs_s[0];                   // descending sort -> block max

  int mydeg[4];
#pragma unroll
  for (int nt = 0; nt < 4; ++nt) mydeg[nt] = degs_s[nt * 16 + l15];

  // per-thread G' element offsets (col base = (w*8+gt*4+quad)*4)
  const int gofs0 = (w * 8 + 0 * 4 + quad) * 4;
  const int gofs1 = (w * 8 + 1 * 4 + quad) * 4;

  float cst[2][4] = {{0.f, 0.f, 0.f, 0.f}, {0.f, 0.f, 0.f, 0.f}};
  float hprev[2][4] = {{0.f, 0.f, 0.f, 0.f}, {0.f, 0.f, 0.f, 0.f}};

  uint2 gxA[2][4], gxB[2][4];
  // prologue: gather x-gates for t=0 into gxA
#pragma unroll
  for (int nt = 0; nt < 4; ++nt) {
    const int nb0 = nbr_s[0 * 64 + nt * 16 + l15];
    const bf16* gr = Gp + (size_t)nb0 * 512;
    gxA[0][nt] = *(const uint2*)(gr + gofs0);
    gxA[1][nt] = *(const uint2*)(gr + gofs1);
  }

  for (int t = 0; t < maxdeg; ++t) {
    const int cur = t & 1, nxt = cur ^ 1;
    const int tn = (t + 1 < maxdeg) ? (t + 1) : t;

    // issue next step's gathers into gxB (waited at the rotation below,
    // after ~4k cycles of h-MFMA + cell — latency fully covered)
#pragma unroll
    for (int nt = 0; nt < 4; ++nt) {
      const int nb1 = nbr_s[tn * 64 + nt * 16 + l15];
      const bf16* gr = Gp + (size_t)nb1 * 512;
      gxB[0][nt] = *(const uint2*)(gr + gofs0);
      gxB[1][nt] = *(const uint2*)(gr + gofs1);
    }

    f32x4 acc[2][4];
#pragma unroll
    for (int gt = 0; gt < 2; ++gt)
#pragma unroll
      for (int nt = 0; nt < 4; ++nt) acc[gt][nt] = (f32x4){0.f, 0.f, 0.f, 0.f};

    // h-part: gates += Whh_packed @ h^T  (skip at t=0: h0 = 0)
    if (t > 0) {
#pragma unroll
      for (int kt = 0; kt < 4; ++kt) {
#pragma unroll
        for (int nt = 0; nt < 4; ++nt) {
          const int row = nt * 16 + l15;
          const s16x8 ah = ldfrag(Hs[cur] + row * 128 + (((kt * 4 + quad) ^ l15) * 8));
#pragma unroll
          for (int gt = 0; gt < 2; ++gt)
            acc[gt][nt] = MFMA16(Bh[gt][kt], ah, acc[gt][nt]);
        }
      }
    }

    // elementwise cell: lane's f32x4 = all 4 gates of one cell (consumes gxA)
#pragma unroll
    for (int gt = 0; gt < 2; ++gt) {
      const int col = w * 8 + gt * 4 + quad;
#pragma unroll
      for (int nt = 0; nt < 4; ++nt) {
        const int row = nt * 16 + l15;
        const uint2 g = gxA[gt][nt];
        const float g_i = acc[gt][nt][0] + lo2f(g.x);
        const float g_f = acc[gt][nt][1] + hi2f(g.x);
        const float g_g = acc[gt][nt][2] + lo2f(g.y);
        const float g_o = acc[gt][nt][3] + hi2f(g.y);
        const float iv = sigf(g_i), fv = sigf(g_f);
        const float gv = tanhf_(g_g), ov = sigf(g_o);
        const float cn = fv * cst[gt][nt] + iv * gv;
        const float hn_new = ov * tanhf_(cn);
        const bool act = (t < mydeg[nt]);
        if (act) cst[gt][nt] = cn;
        const float hn = act ? hn_new : hprev[gt][nt];
        hprev[gt][nt] = hn;
        Hs[nxt][row * 128 + ((w ^ (row & 15)) * 8) + (col & 7)] = f2bf(hn);
      }
    }

    // rotate prefetched gates into the consume slot (pure reg moves)
#pragma unroll
    for (int gt = 0; gt < 2; ++gt)
#pragma unroll
      for (int nt = 0; nt < 4; ++nt) gxA[gt][nt] = gxB[gt][nt];

    lgkm_barrier();   // single barrier: dbuf writes visible, reads done
  }

  // epilogue: Hs[maxdeg&1] (swizzled) -> hTB
  const bf16* Hf = Hs[maxdeg & 1];
  {
    const int row = tid >> 4, j = tid & 15;       // 64 rows x 16 octs, one per thread
    const int nd = nodes_s[row];
    if (nd >= 0) {
      const s16x8 v = ldfrag(Hf + row * 128 + ((j ^ (row & 15)) * 8));
      *(s16x8*)(hTB + (size_t)nd * HIDD + j * 8) = v;
    }
  }
}

// ------- SAGE: h1n = relu(feat@W_self + hT@W_neigh + b) * rsqrt(deg) -------
// feat read from the ORIGINAL float input; inline f2bf = bit-identical frags.
__global__ __launch_bounds__(256) void sage_kernel(const float* __restrict__ featF,
                                                   const bf16* __restrict__ hTB,
                                                   const bf16* __restrict__ WsT,
                                                   const bf16* __restrict__ WnT,
                                                   const float* __restrict__ b_sage,
                                                   const int* __restrict__ deg,
                                                   bf16* __restrict__ h1n) {
  const int lane = threadIdx.x & 63, wave = threadIdx.x >> 6;
  const int l15 = lane & 15, quad = lane >> 4;
  const int nb = blockIdx.x * 64 + wave * 16;
  int arow = nb + l15; if (arow >= NN) arow = NN - 1;
  s16x8 Fa[4], Ha[4];
#pragma unroll
  for (int kt = 0; kt < 4; ++kt) {
    Fa[kt] = ldfrag_f32(featF + (size_t)arow * HIDD + kt * 32 + quad * 8);
    Ha[kt] = ldfrag(hTB + (size_t)arow * HIDD + kt * 32 + quad * 8);
  }
  int nodes[4]; float nrm[4];
#pragma unroll
  for (int r = 0; r < 4; ++r) {
    const int nd = nb + quad * 4 + r;
    nodes[r] = nd;
    nrm[r] = rsqrtf((float)deg[(nd < NN) ? nd : (NN - 1)]);
  }
  for (int ct = 0; ct < 8; ++ct) {
    const int col = ct * 16 + l15;
    f32x4 acc = {0.f, 0.f, 0.f, 0.f};
#pragma unroll
    for (int kt = 0; kt < 4; ++kt) {
      acc = MFMA16(Fa[kt], ldfrag(WsT + col * HIDD + kt * 32 + quad * 8), acc);
      acc = MFMA16(Ha[kt], ldfrag(WnT + col * HIDD + kt * 32 + quad * 8), acc);
    }
    const float bb = b_sage[col];
#pragma unroll
    for (int r = 0; r < 4; ++r)
      if (nodes[r] < NN) {
        const float v = fmaxf(acc[r] + bb, 0.f) * nrm[r];
        h1n[(size_t)nodes[r] * HIDD + col] = f2bf(v);
      }
  }
}

// ------- GraphConv aggregate: agg[n] = rsqrt(deg[n]) * sum_{t<deg} h1n[nbr[n,t]] -------
__global__ __launch_bounds__(256) void agg_kernel(const bf16* __restrict__ h1n,
                                                  const int* __restrict__ nbr_idx,
                                                  const int* __restrict__ deg,
                                                  bf16* __restrict__ aggB) {
  const int wave = threadIdx.x >> 6, lane = threadIdx.x & 63;
  const int node = blockIdx.x * 4 + wave;
  if (node >= NN) return;
  const int d = deg[node];
  const int idx_l = nbr_idx[node * MAXD + (lane & 15)];   // coalesced, broadcast via shfl
  const int c = lane * 2;
  float a0 = 0.f, a1 = 0.f;
  for (int t = 0; t < d; ++t) {
    const int nbr = __shfl(idx_l, t, 64);
    const __hip_bfloat162 v = *(const __hip_bfloat162*)(h1n + (size_t)nbr * HIDD + c);
    a0 += __bfloat162float(v.x);
    a1 += __bfloat162float(v.y);
  }
  const float nm = rsqrtf((float)d);
  aggB[(size_t)node * HIDD + c]     = f2bf(a0 * nm);
  aggB[(size_t)node * HIDD + c + 1] = f2bf(a1 * nm);
}

// ------- fused GraphConv GEMM + GRU: gout = gru(relu(agg @ W_gc + b_gc)) -------
__global__ __launch_bounds__(256) void gcgru_kernel(const bf16* __restrict__ aggB,
                                                    const bf16* __restrict__ WgT,
                                                    const float* __restrict__ b_gc,
                                                    const bf16* __restrict__ WgruB,
                                                    const float* __restrict__ bih,
                                                    const float* __restrict__ bhh,
                                                    float* __restrict__ gout) {
  __shared__ __align__(16) bf16 H2[64 * 136];     // h2 tile, padded pitch
  const int lane = threadIdx.x & 63, wave = threadIdx.x >> 6;
  const int l15 = lane & 15, quad = lane >> 4;
  const int nb = blockIdx.x * 64 + wave * 16;
  int arow = nb + l15; if (arow >= NN) arow = NN - 1;
  s16x8 A[4];
#pragma unroll
  for (int kt = 0; kt < 4; ++kt) A[kt] = ldfrag(aggB + (size_t)arow * HIDD + kt * 32 + quad * 8);
  // gc: h2 = relu(agg @ W_gc + b) -> LDS (C-layout -> row-major for gru A)
  for (int ct = 0; ct < 8; ++ct) {
    const int col = ct * 16 + l15;
    f32x4 acc = {0.f, 0.f, 0.f, 0.f};
#pragma unroll
    for (int kt = 0; kt < 4; ++kt)
      acc = MFMA16(A[kt], ldfrag(WgT + col * HIDD + kt * 32 + quad * 8), acc);
    const float bb = b_gc[col];
#pragma unroll
    for (int r = 0; r < 4; ++r)
      H2[(wave * 16 + quad * 4 + r) * 136 + col] = f2bf(fmaxf(acc[r] + bb, 0.f));
  }
  __syncthreads();
  // gru over rows wave*16 + l15
  s16x8 A2[4];
#pragma unroll
  for (int kt = 0; kt < 4; ++kt)
    A2[kt] = ldfrag(H2 + (wave * 16 + l15) * 136 + kt * 32 + quad * 8);
  f32x4 acc[6];
#pragma unroll
  for (int ct = 0; ct < 6; ++ct) {
    f32x4 a = {0.f, 0.f, 0.f, 0.f};
#pragma unroll
    for (int kt = 0; kt < 4; ++kt)
      a = MFMA16(A2[kt], ldfrag(WgruB + (ct * 16 + l15) * HIDD + kt * 32 + quad * 8), a);
    acc[ct] = a;
  }
#pragma unroll
  for (int u = 0; u < 2; ++u) {
    const int cu = 16 * u + l15;
    const float br = bih[cu] + bhh[cu];
    const float bz = bih[32 + cu] + bhh[32 + cu];
    const float bni = bih[64 + cu];
    const float bnh = bhh[64 + cu];
#pragma unroll
    for (int r = 0; r < 4; ++r) {
      const int node = nb + quad * 4 + r;
      if (node < NN) {
        const float rv = sigf(acc[u][r] + br);
        const float zv = sigf(acc[2 + u][r] + bz);
        const float nv = tanhf_(acc[4 + u][r] + bni + rv * bnh);
        gout[(size_t)node * GRUH + cu] = (1.f - zv) * nv;
      }
    }
  }
}

// ------- two-phase per-graph mean pool + classifier -------
#define POOL_CHUNK 512
__global__ __launch_bounds__(256) void pool_partial_kernel(const float* __restrict__ gout,
                                                           const int* __restrict__ gids,
                                                           float* __restrict__ sums,
                                                           float* __restrict__ cnts) {
  __shared__ float ls[NGRAPH * GRUH];
  __shared__ float lc[NGRAPH];
  const int tid = threadIdx.x;
  for (int i = tid; i < NGRAPH * GRUH; i += 256) ls[i] = 0.f;
  if (tid < NGRAPH) lc[tid] = 0.f;
  __syncthreads();

  const int wave = tid >> 6, lane = tid & 63;
  const int c = lane & 31, half = lane >> 5;
  const int base = blockIdx.x * POOL_CHUNK + wave * (POOL_CHUNK / 8);

  float accv = 0.f, ccnt = 0.f;
  int curg = -1;
  for (int it = 0; it < POOL_CHUNK / 16; ++it) {
    const int n = base + it * 2 + half;
    if (n < NN) {
      const int g = gids[n];
      const float v = gout[(size_t)n * GRUH + c];
      if (g != curg) {
        if (curg >= 0) {
          atomicAdd(&ls[curg * GRUH + c], accv);
          if (c == 0) atomicAdd(&lc[curg], ccnt);
        }
        curg = g; accv = 0.f; ccnt = 0.f;
      }
      accv += v; ccnt += 1.f;
    }
  }
  if (curg >= 0) {
    atomicAdd(&ls[curg * GRUH + c], accv);
    if (c == 0) atomicAdd(&lc[curg], ccnt);
  }
  __syncthreads();
  for (int i = tid; i < NGRAPH * GRUH; i += 256)
    if (ls[i] != 0.f) atomicAdd(&sums[i], ls[i]);
  if (tid < NGRAPH && lc[tid] != 0.f) atomicAdd(&cnts[tid], lc[tid]);
}

__global__ __launch_bounds__(256) void pool_final_kernel(const float* __restrict__ sums,
                                                         const float* __restrict__ cnts,
                                                         const float* __restrict__ Wcls,
                                                         const float* __restrict__ bcls,
                                                         float* __restrict__ out) {
  const int idx = blockIdx.x * blockDim.x + threadIdx.x;
  if (idx >= NGRAPH * NCLSS) return;
  const int g = idx / NCLSS, k = idx % NCLSS;
  const float inv = 1.0f / cnts[g];
  float acc = bcls[k];
#pragma unroll
  for (int cc = 0; cc < GRUH; ++cc)
    acc += sums[g * GRUH + cc] * inv * Wcls[cc * NCLSS + k];
  out[idx] = acc;
}

extern "C" void kernel_launch(void* const* d_in, const int* in_sizes, int n_in,
                              void* d_out, int out_size, void* d_ws, size_t ws_size,
                              hipStream_t stream) {
  const float* feature  = (const float*)d_in[0];
  const int*   nbr_idx  = (const int*)d_in[1];
  const int*   deg      = (const int*)d_in[2];
  const int*   gids     = (const int*)d_in[3];
  const float* lstm_Wih = (const float*)d_in[4];
  const float* lstm_Whh = (const float*)d_in[5];
  const float* lstm_bih = (const float*)d_in[6];
  const float* lstm_bhh = (const float*)d_in[7];
  const float* W_self   = (const float*)d_in[8];
  const float* W_neigh  = (const float*)d_in[9];
  const float* b_sage   = (const float*)d_in[10];
  const float* W_gc     = (const float*)d_in[11];
  const float* b_gc     = (const float*)d_in[12];
  const float* Wih_gru  = (const float*)d_in[13];
  const float* bih_gru  = (const float*)d_in[14];
  const float* bhh_gru  = (const float*)d_in[15];
  const float* W_cls    = (const float*)d_in[16];
  const float* b_cls    = (const float*)d_in[17];

  // workspace: peak 64.8 MB (within the 65.4 MB proven bound).
  // Timeline aliases: hTB at 0 (lstm out, sage in), gout aliases it after
  // sage; Gp dead after lstm -> h1nB/aggB inside its region.
  char* ws = (char*)d_ws;
  bf16*  hTB   = (bf16*)(ws + 0);           // [NN,128] 12.8MB
  float* gout  = (float*)(ws + 0);          // alias hTB (gcgru out, 6.4MB)
  bf16*  Gp    = (bf16*)(ws + 12800000);    // [NN,512] 51.2MB (dead after lstm)
  bf16*  h1nB  = (bf16*)(ws + 12800000);    // alias Gp[0:12.8M] (sage out, agg in)
  bf16*  aggB  = (bf16*)(ws + 25600000);    // alias Gp[12.8:25.6M] (agg out, gcgru in)
  const size_t wo = 64000000;
  bf16*  WihB  = (bf16*)(ws + wo);
  bf16*  WhhB  = (bf16*)(ws + wo + 131072);
  bf16*  WsT   = (bf16*)(ws + wo + 262144);
  bf16*  WnT   = (bf16*)(ws + wo + 294912);
  bf16*  WgT   = (bf16*)(ws + wo + 327680);
  bf16*  WgruB = (bf16*)(ws + wo + 360448);
  float* biasS = (float*)(ws + wo + 385024);
  int*   perm  = (int*)(ws + 64500000);
  int*   hist  = (int*)(ws + 64800000);     // [17]
  int*   resv  = hist + 17;                 // [17]
  float* psums = (float*)(ws + 64801216);   // [50][32]
  float* pcnts = psums + NGRAPH * GRUH;     // [50]

  prep_kernel<<<754, 256, 0, stream>>>(lstm_Wih, lstm_Whh, lstm_bih, lstm_bhh,
                                       W_self, W_neigh, W_gc, Wih_gru,
                                       WihB, WhhB, WsT, WnT, WgT, WgruB, biasS);
  hipMemsetAsync(hist, 0, 34 * sizeof(int), stream);
  hipMemsetAsync(psums, 0, (NGRAPH * GRUH + NGRAPH) * sizeof(float), stream);
  hist_kernel<<<196, 256, 0, stream>>>(deg, hist);
  scatter_kernel<<<196, 256, 0, stream>>>(deg, hist, resv, perm);
  ggemm_kernel<<<782, 256, 0, stream>>>(feature, WihB, biasS, Gp);
  lstm_kernel<<<782, 1024, 0, stream>>>(Gp, WhhB, nbr_idx, deg, perm, hTB);
  sage_kernel<<<782, 256, 0, stream>>>(feature, hTB, WsT, WnT, b_sage, deg, h1nB);
  agg_kernel<<<12500, 256, 0, stream>>>(h1nB, nbr_idx, deg, aggB);
  gcgru_kernel<<<782, 256, 0, stream>>>(aggB, WgT, b_gc, WgruB, bih_gru, bhh_gru, gout);
  pool_partial_kernel<<<(NN + POOL_CHUNK - 1) / POOL_CHUNK, 256, 0, stream>>>(gout, gids, psums, pcnts);
  pool_final_kernel<<<2, 256, 0, stream>>>(psums, pcnts, W_cls, b_cls, (float*)d_out);
}

// Round 8
// 459.732 us; speedup vs baseline: 1.1227x; 1.0437x over previous
//
#include <hip/hip_runtime.h>
#include <hip/hip_bf16.h>

// GCN_71451075936314 on gfx950.
// R17: (a) lstm reverted to R13-exact loop (measured 177us). R16 evidence:
//      reg-prefetch rotation HURT (216us, WRITE 12.5->36.7MB, VGPR stuck 64
//      => gxB spilled; reg file is full at this layout — line abandoned).
//      (b) rest-side fusion: agg + gcgru + pool_partial merged into ONE
//      kernel (aggru): block aggregates its 64 nodes' neighbors into LDS,
//      gc-GEMM reads LDS, GRU outputs accumulate per-graph (<=2 graphs per
//      64-node block) in LDS then one atomic flush. Deletes aggB (25.6MB
//      round trip), gout (12.8MB round trip), 2 dispatches.
//      Cross-round accounting: rest = 212-265us >= 55% of wall; this is
//      the first direct attack on it.

#define NN     50000
#define HIDD   128
#define MAXD   16
#define NGRAPH 50
#define NCLSS  10
#define GRUH   32

typedef __attribute__((ext_vector_type(8))) short s16x8;    // 8 bf16 (4 VGPRs)
typedef __attribute__((ext_vector_type(4))) float f32x4;
typedef __hip_bfloat16 bf16;

#define MFMA16(a,b,c)  __builtin_amdgcn_mfma_f32_16x16x32_bf16((a),(b),(c),0,0,0)

__device__ __forceinline__ float bf2f(bf16 x) { return __bfloat162float(x); }
__device__ __forceinline__ bf16  f2bf(float x) { return __float2bfloat16(x); }
__device__ __forceinline__ s16x8 ldfrag(const bf16* p) { return *(const s16x8*)p; }

__device__ __forceinline__ s16x8 ldfrag_f32(const float* p) {
  const float4 a = *(const float4*)p;
  const float4 b = *(const float4*)(p + 4);
  union { s16x8 v; bf16 h[8]; } r;
  r.h[0] = f2bf(a.x); r.h[1] = f2bf(a.y); r.h[2] = f2bf(a.z); r.h[3] = f2bf(a.w);
  r.h[4] = f2bf(b.x); r.h[5] = f2bf(b.y); r.h[6] = f2bf(b.z); r.h[7] = f2bf(b.w);
  return r.v;
}

__device__ __forceinline__ float sigf(float x) {
  return __builtin_amdgcn_rcpf(1.0f + __expf(-x));
}
__device__ __forceinline__ float tanhf_(float x) {
  return 1.0f - 2.0f * __builtin_amdgcn_rcpf(1.0f + __expf(2.0f * x));
}

__device__ __forceinline__ unsigned packbf2(float a, float b) {
  union { bf16 h; unsigned short u; } x, y;
  x.h = f2bf(a); y.h = f2bf(b);
  return (unsigned)x.u | ((unsigned)y.u << 16);
}
__device__ __forceinline__ float lo2f(unsigned u) { return __uint_as_float(u << 16); }
__device__ __forceinline__ float hi2f(unsigned u) { return __uint_as_float(u & 0xffff0000u); }

// barrier that drains LDS ops only — global loads stay in flight
__device__ __forceinline__ void lgkm_barrier() {
  asm volatile("s_waitcnt lgkmcnt(0)\n\ts_barrier" ::: "memory");
}

// ---------------- prep: weight bf16 casts + transposes + bias fold ----------------
__global__ __launch_bounds__(256) void prep_kernel(const float* __restrict__ Wih,
                            const float* __restrict__ Whh, const float* __restrict__ bih,
                            const float* __restrict__ bhh, const float* __restrict__ Wself,
                            const float* __restrict__ Wneigh, const float* __restrict__ Wgc,
                            const float* __restrict__ Wgru,
                            bf16* WihB, bf16* WhhB, bf16* WsT, bf16* WnT,
                            bf16* WgT, bf16* WgruB, float* biasS) {
  const int total = 2 * 65536 + 3 * 16384 + 12288 + 512;   // 193024
  int stride = gridDim.x * blockDim.x;
  for (int idx = blockIdx.x * blockDim.x + threadIdx.x; idx < total; idx += stride) {
    int j = idx;
    if (j < 65536) { WihB[j] = f2bf(Wih[j]); continue; }
    j -= 65536;
    if (j < 65536) { WhhB[j] = f2bf(Whh[j]); continue; }
    j -= 65536;
    if (j < 16384) { int c = j >> 7, k = j & 127; WsT[j] = f2bf(Wself[k * HIDD + c]); continue; }
    j -= 16384;
    if (j < 16384) { int c = j >> 7, k = j & 127; WnT[j] = f2bf(Wneigh[k * HIDD + c]); continue; }
    j -= 16384;
    if (j < 16384) { int c = j >> 7, k = j & 127; WgT[j] = f2bf(Wgc[k * HIDD + c]); continue; }
    j -= 16384;
    if (j < 12288) { WgruB[j] = f2bf(Wgru[j]); continue; }
    j -= 12288;
    biasS[j] = bih[j] + bhh[j];
  }
}

// ---------------- counting sort by degree (DESCENDING): LDS hist ----------------
__global__ __launch_bounds__(256) void hist_kernel(const int* __restrict__ deg, int* hist) {
  __shared__ int lh[17];
  const int tid = threadIdx.x;
  if (tid < 17) lh[tid] = 0;
  __syncthreads();
  const int i = blockIdx.x * 256 + tid;
  if (i < NN) atomicAdd(&lh[deg[i]], 1);
  __syncthreads();
  if (tid < 17 && lh[tid]) atomicAdd(&hist[tid], lh[tid]);
}

__global__ __launch_bounds__(256) void scatter_kernel(const int* __restrict__ deg,
                                                      const int* __restrict__ hist,
                                                      int* __restrict__ resv,
                                                      int* __restrict__ perm) {
  __shared__ int lh[17], lbase[17], lpos[17];
  const int tid = threadIdx.x;
  if (tid < 17) { lh[tid] = 0; lpos[tid] = 0; }
  __syncthreads();
  const int i = blockIdx.x * 256 + tid;
  const int d = (i < NN) ? deg[i] : -1;
  if (d >= 0) atomicAdd(&lh[d], 1);
  __syncthreads();
  if (tid < 17) {
    int pre = 0;
    for (int k = tid + 1; k < 17; ++k) pre += hist[k];   // descending: larger degs first
    lbase[tid] = pre + (lh[tid] ? atomicAdd(&resv[tid], lh[tid]) : 0);
  }
  __syncthreads();
  if (d >= 0) {
    const int p = lbase[d] + atomicAdd(&lpos[d], 1);
    perm[p] = i;
  }
}

// ---------------- G-GEMM: G'[n][hcol*4+gate] = feat[n] @ Wih^T + bias ----------------
__global__ __launch_bounds__(256) void ggemm_kernel(const float* __restrict__ featF,
                                                    const bf16* __restrict__ WihB,
                                                    const float* __restrict__ biasS,
                                                    bf16* __restrict__ Gp) {
  const int lane = threadIdx.x & 63, wave = threadIdx.x >> 6;
  const int l15 = lane & 15, quad = lane >> 4;
  const int nb = blockIdx.x * 64;

  s16x8 Bx[4][4];
#pragma unroll
  for (int nt = 0; nt < 4; ++nt) {
    int arow = nb + nt * 16 + l15; if (arow >= NN) arow = NN - 1;
#pragma unroll
    for (int kt = 0; kt < 4; ++kt)
      Bx[nt][kt] = ldfrag_f32(featF + (size_t)arow * HIDD + kt * 32 + quad * 8);
  }

  for (int hg = wave * 8; hg < wave * 8 + 8; ++hg) {
    const int wr = (l15 & 3) * HIDD + hg * 4 + (l15 >> 2);
    s16x8 Aw[4];
#pragma unroll
    for (int kt = 0; kt < 4; ++kt)
      Aw[kt] = ldfrag(WihB + (size_t)wr * HIDD + kt * 32 + quad * 8);
    const int hcol = hg * 4 + quad;
    float b0 = biasS[0 * HIDD + hcol], b1 = biasS[1 * HIDD + hcol];
    float b2 = biasS[2 * HIDD + hcol], b3 = biasS[3 * HIDD + hcol];
#pragma unroll
    for (int nt = 0; nt < 4; ++nt) {
      f32x4 acc = {0.f, 0.f, 0.f, 0.f};
#pragma unroll
      for (int kt = 0; kt < 4; ++kt)
        acc = MFMA16(Aw[kt], Bx[nt][kt], acc);
      const int node = nb + nt * 16 + l15;
      if (node < NN) {
        unsigned u0 = packbf2(acc[0] + b0, acc[1] + b1);
        unsigned u1 = packbf2(acc[2] + b2, acc[3] + b3);
        *(uint2*)(Gp + (size_t)node * 512 + hcol * 4) = make_uint2(u0, u1);
      }
    }
  }
}

// ---------------- LSTM recurrence: 1024 thr / 16 waves / 64 nodes ----------------
// R13-exact: h-part only; x-gates gathered from G' at step top, consumed in
// the same step's cell. Transposed-C MFMA, packed vrows. Whh pinned 32 VGPR.
__global__ __launch_bounds__(1024, 4) void lstm_kernel(const bf16* __restrict__ Gp,
                                                       const bf16* __restrict__ WhhB,
                                                       const int* __restrict__ nbr_idx,
                                                       const int* __restrict__ deg,
                                                       const int* __restrict__ perm,
                                                       bf16* __restrict__ hTB) {
  __shared__ __align__(16) bf16 Hs[2][64 * 128];  // 32KB: h dbuf, oct-xor swizzled
  __shared__ int nbr_s[16 * 64];                  // [t][row]
  __shared__ int nodes_s[64];
  __shared__ int degs_s[64];

  const int tid = threadIdx.x;
  const int lane = tid & 63, w = tid >> 6;        // w = hcol-block 0..15
  const int l15 = lane & 15, quad = lane >> 4;
  const int base = blockIdx.x * 64;

  if (tid < 64) {
    const int gi = base + tid;
    const int nd = (gi < NN) ? perm[gi] : -1;
    nodes_s[tid] = nd;
    degs_s[tid] = (nd >= 0) ? deg[nd] : 0;
  }
  __syncthreads();
  {
    const int row = tid & 63, t = tid >> 6;       // exactly one entry per thread
    const int nd = nodes_s[row];
    nbr_s[t * 64 + row] = (nd >= 0) ? nbr_idx[nd * MAXD + t] : 0;
  }

  // pinned Whh packed frags: vrow v=l15 -> Whh row (v&3)*128 + w*8 + gt*4 + (v>>2)
  s16x8 Bh[2][4];
#pragma unroll
  for (int gt = 0; gt < 2; ++gt) {
    const int wr = (l15 & 3) * HIDD + w * 8 + gt * 4 + (l15 >> 2);
#pragma unroll
    for (int kt = 0; kt < 4; ++kt) {
      Bh[gt][kt] = ldfrag(WhhB + (size_t)wr * HIDD + kt * 32 + quad * 8);
      asm volatile("" : "+v"(Bh[gt][kt]));
    }
  }

  __syncthreads();                                // nbr_s visible
  const int maxdeg = degs_s[0];                   // descending sort -> block max

  int mydeg[4];
#pragma unroll
  for (int nt = 0; nt < 4; ++nt) mydeg[nt] = degs_s[nt * 16 + l15];

  // per-thread G' element offsets (col base = (w*8+gt*4+quad)*4)
  const int gofs0 = (w * 8 + 0 * 4 + quad) * 4;
  const int gofs1 = (w * 8 + 1 * 4 + quad) * 4;

  float cst[2][4] = {{0.f, 0.f, 0.f, 0.f}, {0.f, 0.f, 0.f, 0.f}};
  float hprev[2][4] = {{0.f, 0.f, 0.f, 0.f}, {0.f, 0.f, 0.f, 0.f}};

  for (int t = 0; t < maxdeg; ++t) {
    const int cur = t & 1, nxt = cur ^ 1;

    // gather x-gates for this step (consumed in cell; latency hidden by MFMA)
    uint2 gx[2][4];
#pragma unroll
    for (int nt = 0; nt < 4; ++nt) {
      const int nb1 = nbr_s[t * 64 + nt * 16 + l15];
      const bf16* gr = Gp + (size_t)nb1 * 512;
      gx[0][nt] = *(const uint2*)(gr + gofs0);
      gx[1][nt] = *(const uint2*)(gr + gofs1);
    }

    f32x4 acc[2][4];
#pragma unroll
    for (int gt = 0; gt < 2; ++gt)
#pragma unroll
      for (int nt = 0; nt < 4; ++nt) acc[gt][nt] = (f32x4){0.f, 0.f, 0.f, 0.f};

    // h-part: gates += Whh_packed @ h^T  (skip at t=0: h0 = 0)
    if (t > 0) {
#pragma unroll
      for (int kt = 0; kt < 4; ++kt) {
#pragma unroll
        for (int nt = 0; nt < 4; ++nt) {
          const int row = nt * 16 + l15;
          const s16x8 ah = ldfrag(Hs[cur] + row * 128 + (((kt * 4 + quad) ^ l15) * 8));
#pragma unroll
          for (int gt = 0; gt < 2; ++gt)
            acc[gt][nt] = MFMA16(Bh[gt][kt], ah, acc[gt][nt]);
        }
      }
    }

    // elementwise cell: lane's f32x4 = all 4 gates of one cell
#pragma unroll
    for (int gt = 0; gt < 2; ++gt) {
      const int col = w * 8 + gt * 4 + quad;
#pragma unroll
      for (int nt = 0; nt < 4; ++nt) {
        const int row = nt * 16 + l15;
        const uint2 g = gx[gt][nt];
        const float g_i = acc[gt][nt][0] + lo2f(g.x);
        const float g_f = acc[gt][nt][1] + hi2f(g.x);
        const float g_g = acc[gt][nt][2] + lo2f(g.y);
        const float g_o = acc[gt][nt][3] + hi2f(g.y);
        const float iv = sigf(g_i), fv = sigf(g_f);
        const float gv = tanhf_(g_g), ov = sigf(g_o);
        const float cn = fv * cst[gt][nt] + iv * gv;
        const float hn_new = ov * tanhf_(cn);
        const bool act = (t < mydeg[nt]);
        if (act) cst[gt][nt] = cn;
        const float hn = act ? hn_new : hprev[gt][nt];
        hprev[gt][nt] = hn;
        Hs[nxt][row * 128 + ((w ^ (row & 15)) * 8) + (col & 7)] = f2bf(hn);
      }
    }
    lgkm_barrier();   // single barrier: dbuf writes visible, reads done
  }

  // epilogue: Hs[maxdeg&1] (swizzled) -> hTB
  const bf16* Hf = Hs[maxdeg & 1];
  {
    const int row = tid >> 4, j = tid & 15;       // 64 rows x 16 octs, one per thread
    const int nd = nodes_s[row];
    if (nd >= 0) {
      const s16x8 v = ldfrag(Hf + row * 128 + ((j ^ (row & 15)) * 8));
      *(s16x8*)(hTB + (size_t)nd * HIDD + j * 8) = v;
    }
  }
}

// ------- SAGE: h1n = relu(feat@W_self + hT@W_neigh + b) * rsqrt(deg) -------
__global__ __launch_bounds__(256) void sage_kernel(const float* __restrict__ featF,
                                                   const bf16* __restrict__ hTB,
                                                   const bf16* __restrict__ WsT,
                                                   const bf16* __restrict__ WnT,
                                                   const float* __restrict__ b_sage,
                                                   const int* __restrict__ deg,
                                                   bf16* __restrict__ h1n) {
  const int lane = threadIdx.x & 63, wave = threadIdx.x >> 6;
  const int l15 = lane & 15, quad = lane >> 4;
  const int nb = blockIdx.x * 64 + wave * 16;
  int arow = nb + l15; if (arow >= NN) arow = NN - 1;
  s16x8 Fa[4], Ha[4];
#pragma unroll
  for (int kt = 0; kt < 4; ++kt) {
    Fa[kt] = ldfrag_f32(featF + (size_t)arow * HIDD + kt * 32 + quad * 8);
    Ha[kt] = ldfrag(hTB + (size_t)arow * HIDD + kt * 32 + quad * 8);
  }
  int nodes[4]; float nrm[4];
#pragma unroll
  for (int r = 0; r < 4; ++r) {
    const int nd = nb + quad * 4 + r;
    nodes[r] = nd;
    nrm[r] = rsqrtf((float)deg[(nd < NN) ? nd : (NN - 1)]);
  }
  for (int ct = 0; ct < 8; ++ct) {
    const int col = ct * 16 + l15;
    f32x4 acc = {0.f, 0.f, 0.f, 0.f};
#pragma unroll
    for (int kt = 0; kt < 4; ++kt) {
      acc = MFMA16(Fa[kt], ldfrag(WsT + col * HIDD + kt * 32 + quad * 8), acc);
      acc = MFMA16(Ha[kt], ldfrag(WnT + col * HIDD + kt * 32 + quad * 8), acc);
    }
    const float bb = b_sage[col];
#pragma unroll
    for (int r = 0; r < 4; ++r)
      if (nodes[r] < NN) {
        const float v = fmaxf(acc[r] + bb, 0.f) * nrm[r];
        h1n[(size_t)nodes[r] * HIDD + col] = f2bf(v);
      }
  }
}

// ------- FUSED: agg gather -> gc GEMM -> GRU -> per-graph pool partial -------
// Block = 64 nodes. Phase A: aggregate neighbor h1n rows into LDS Ag.
// Phase B: h2 = relu(Ag @ W_gc + b) -> H2 (LDS); gru GEMM from H2.
// Phase C: gru outputs accumulate into <=2 per-graph LDS slots (64
// consecutive nodes span <=2 graphs at 1000 nodes/graph), one atomic flush.
__global__ __launch_bounds__(256) void aggru_kernel(const bf16* __restrict__ h1n,
                                                    const int* __restrict__ nbr_idx,
                                                    const int* __restrict__ deg,
                                                    const int* __restrict__ gids,
                                                    const bf16* __restrict__ WgT,
                                                    const float* __restrict__ b_gc,
                                                    const bf16* __restrict__ WgruB,
                                                    const float* __restrict__ bih,
                                                    const float* __restrict__ bhh,
                                                    float* __restrict__ psums,
                                                    float* __restrict__ pcnts) {
  __shared__ __align__(16) bf16 Ag[64 * 136];     // aggregated rows, padded pitch
  __shared__ __align__(16) bf16 H2[64 * 136];     // h2 tile, padded pitch
  __shared__ float psl[2 * GRUH];
  __shared__ float pcl[2];
  const int tid = threadIdx.x;
  const int lane = tid & 63, wave = tid >> 6;
  const int l15 = lane & 15, quad = lane >> 4;
  const int nbb = blockIdx.x * 64;
  const int nb = nbb + wave * 16;

  if (tid < 2 * GRUH) psl[tid] = 0.f;
  if (tid < 2) pcl[tid] = 0.f;

  // phase A: agg[n] = rsqrt(deg) * sum_{t<deg} h1n[nbr[n,t]]  -> Ag (LDS)
  const int c2 = lane * 2;
  for (int i = 0; i < 16; ++i) {
    const int node = nb + i;
    float a0 = 0.f, a1 = 0.f;
    if (node < NN) {
      const int d = deg[node];
      const int idx_l = nbr_idx[node * MAXD + (lane & 15)];  // bcast via shfl
      for (int t = 0; t < d; ++t) {
        const int nbr = __shfl(idx_l, t, 64);
        const __hip_bfloat162 v = *(const __hip_bfloat162*)(h1n + (size_t)nbr * HIDD + c2);
        a0 += __bfloat162float(v.x);
        a1 += __bfloat162float(v.y);
      }
      const float nm = rsqrtf((float)d);
      a0 *= nm; a1 *= nm;
    }
    Ag[(wave * 16 + i) * 136 + c2]     = f2bf(a0);
    Ag[(wave * 16 + i) * 136 + c2 + 1] = f2bf(a1);
  }
  __syncthreads();

  // phase B1: gc GEMM from Ag; h2 = relu(.) -> H2
  s16x8 A[4];
#pragma unroll
  for (int kt = 0; kt < 4; ++kt)
    A[kt] = ldfrag(Ag + (wave * 16 + l15) * 136 + kt * 32 + quad * 8);
  for (int ct = 0; ct < 8; ++ct) {
    const int col = ct * 16 + l15;
    f32x4 acc = {0.f, 0.f, 0.f, 0.f};
#pragma unroll
    for (int kt = 0; kt < 4; ++kt)
      acc = MFMA16(A[kt], ldfrag(WgT + col * HIDD + kt * 32 + quad * 8), acc);
    const float bb = b_gc[col];
#pragma unroll
    for (int r = 0; r < 4; ++r)
      H2[(wave * 16 + quad * 4 + r) * 136 + col] = f2bf(fmaxf(acc[r] + bb, 0.f));
  }
  __syncthreads();

  // phase B2: gru GEMM over rows wave*16 + l15
  s16x8 A2[4];
#pragma unroll
  for (int kt = 0; kt < 4; ++kt)
    A2[kt] = ldfrag(H2 + (wave * 16 + l15) * 136 + kt * 32 + quad * 8);
  f32x4 acc[6];
#pragma unroll
  for (int ct = 0; ct < 6; ++ct) {
    f32x4 a = {0.f, 0.f, 0.f, 0.f};
#pragma unroll
    for (int kt = 0; kt < 4; ++kt)
      a = MFMA16(A2[kt], ldfrag(WgruB + (ct * 16 + l15) * HIDD + kt * 32 + quad * 8), a);
    acc[ct] = a;
  }

  // phase C: gru activation + per-graph accumulate (block spans <=2 graphs)
  const int g0 = gids[nbb];
  int mynode[4], mygs[4];
#pragma unroll
  for (int r = 0; r < 4; ++r) {
    const int nd = nb + quad * 4 + r;
    mynode[r] = nd;
    mygs[r] = (nd < NN) ? (gids[nd] - g0) : 0;
  }
#pragma unroll
  for (int u = 0; u < 2; ++u) {
    const int cu = 16 * u + l15;
    const float br = bih[cu] + bhh[cu];
    const float bz = bih[32 + cu] + bhh[32 + cu];
    const float bni = bih[64 + cu];
    const float bnh = bhh[64 + cu];
#pragma unroll
    for (int r = 0; r < 4; ++r) {
      if (mynode[r] < NN) {
        const float rv = sigf(acc[u][r] + br);
        const float zv = sigf(acc[2 + u][r] + bz);
        const float nv = tanhf_(acc[4 + u][r] + bni + rv * bnh);
        const float v = (1.f - zv) * nv;
        atomicAdd(&psl[mygs[r] * GRUH + cu], v);
        if (u == 0 && l15 == 0) atomicAdd(&pcl[mygs[r]], 1.f);
      }
    }
  }
  __syncthreads();
  if (tid < 2 * GRUH) {
    const int s = tid >> 5, c = tid & 31;
    const float vv = psl[tid];
    if (vv != 0.f && g0 + s < NGRAPH) atomicAdd(&psums[(g0 + s) * GRUH + c], vv);
  }
  if (tid < 2) {
    if (pcl[tid] != 0.f && g0 + tid < NGRAPH) atomicAdd(&pcnts[g0 + tid], pcl[tid]);
  }
}

// ------- final: per-graph mean + classifier -------
__global__ __launch_bounds__(256) void pool_final_kernel(const float* __restrict__ sums,
                                                         const float* __restrict__ cnts,
                                                         const float* __restrict__ Wcls,
                                                         const float* __restrict__ bcls,
                                                         float* __restrict__ out) {
  const int idx = blockIdx.x * blockDim.x + threadIdx.x;
  if (idx >= NGRAPH * NCLSS) return;
  const int g = idx / NCLSS, k = idx % NCLSS;
  const float inv = 1.0f / cnts[g];
  float acc = bcls[k];
#pragma unroll
  for (int cc = 0; cc < GRUH; ++cc)
    acc += sums[g * GRUH + cc] * inv * Wcls[cc * NCLSS + k];
  out[idx] = acc;
}

extern "C" void kernel_launch(void* const* d_in, const int* in_sizes, int n_in,
                              void* d_out, int out_size, void* d_ws, size_t ws_size,
                              hipStream_t stream) {
  const float* feature  = (const float*)d_in[0];
  const int*   nbr_idx  = (const int*)d_in[1];
  const int*   deg      = (const int*)d_in[2];
  const int*   gids     = (const int*)d_in[3];
  const float* lstm_Wih = (const float*)d_in[4];
  const float* lstm_Whh = (const float*)d_in[5];
  const float* lstm_bih = (const float*)d_in[6];
  const float* lstm_bhh = (const float*)d_in[7];
  const float* W_self   = (const float*)d_in[8];
  const float* W_neigh  = (const float*)d_in[9];
  const float* b_sage   = (const float*)d_in[10];
  const float* W_gc     = (const float*)d_in[11];
  const float* b_gc     = (const float*)d_in[12];
  const float* Wih_gru  = (const float*)d_in[13];
  const float* bih_gru  = (const float*)d_in[14];
  const float* bhh_gru  = (const float*)d_in[15];
  const float* W_cls    = (const float*)d_in[16];
  const float* b_cls    = (const float*)d_in[17];

  // workspace: peak 64.8 MB (within the 65.4 MB proven bound).
  // Aliases: hTB at 0 (lstm out, sage in); Gp dead after lstm -> h1nB
  // inside its region. aggB/gout deleted (fused into aggru).
  char* ws = (char*)d_ws;
  bf16*  hTB   = (bf16*)(ws + 0);           // [NN,128] 12.8MB
  bf16*  Gp    = (bf16*)(ws + 12800000);    // [NN,512] 51.2MB (dead after lstm)
  bf16*  h1nB  = (bf16*)(ws + 12800000);    // alias Gp[0:12.8M] (sage out, aggru in)
  const size_t wo = 64000000;
  bf16*  WihB  = (bf16*)(ws + wo);
  bf16*  WhhB  = (bf16*)(ws + wo + 131072);
  bf16*  WsT   = (bf16*)(ws + wo + 262144);
  bf16*  WnT   = (bf16*)(ws + wo + 294912);
  bf16*  WgT   = (bf16*)(ws + wo + 327680);
  bf16*  WgruB = (bf16*)(ws + wo + 360448);
  float* biasS = (float*)(ws + wo + 385024);
  int*   perm  = (int*)(ws + 64500000);
  int*   hist  = (int*)(ws + 64800000);     // [17]
  int*   resv  = hist + 17;                 // [17]
  float* psums = (float*)(ws + 64801216);   // [50][32]
  float* pcnts = psums + NGRAPH * GRUH;     // [50]

  prep_kernel<<<754, 256, 0, stream>>>(lstm_Wih, lstm_Whh, lstm_bih, lstm_bhh,
                                       W_self, W_neigh, W_gc, Wih_gru,
                                       WihB, WhhB, WsT, WnT, WgT, WgruB, biasS);
  hipMemsetAsync(hist, 0, 34 * sizeof(int), stream);
  hipMemsetAsync(psums, 0, (NGRAPH * GRUH + NGRAPH) * sizeof(float), stream);
  hist_kernel<<<196, 256, 0, stream>>>(deg, hist);
  scatter_kernel<<<196, 256, 0, stream>>>(deg, hist, resv, perm);
  ggemm_kernel<<<782, 256, 0, stream>>>(feature, WihB, biasS, Gp);
  lstm_kernel<<<782, 1024, 0, stream>>>(Gp, WhhB, nbr_idx, deg, perm, hTB);
  sage_kernel<<<782, 256, 0, stream>>>(feature, hTB, WsT, WnT, b_sage, deg, h1nB);
  aggru_kernel<<<782, 256, 0, stream>>>(h1nB, nbr_idx, deg, gids, WgT, b_gc,
                                        WgruB, bih_gru, bhh_gru, psums, pcnts);
  pool_final_kernel<<<2, 256, 0, stream>>>(psums, pcnts, W_cls, b_cls, (float*)d_out);
}

// Round 9
// 415.697 us; speedup vs baseline: 1.2416x; 1.1059x over previous
//
#include <hip/hip_runtime.h>
#include <hip/hip_bf16.h>

// GCN_71451075936314 on gfx950.
// R18: two point fixes on R17's measurements (lstm 179us clean; rest 281us,
//      +16 vs unfused despite -38MB traffic => aggru phase-A gather was
//      16x SERIALIZED: each wave walked 16 nodes x d iters).
//      (a) aggru phase A -> node-parallel: 4 threads/node (32 cols each,
//          f32 reg accumulation), nbr lists in LDS. 782x64 = 50k concurrent
//          node-gathers (same parallelism as the old 12500-block agg) while
//          keeping the fusion's round-trip savings.
//      (b) SAGE folded into lstm epilogue: block's final h rows are already
//          in LDS; run the sage GEMM there (16 waves = 4 row-tiles x 4
//          col-pairs, feature f32 from global, Ws/Wn from L2) and write h1n
//          directly. Deletes sage kernel + hTB round trip (25.6MB).
//      Recurrence loop is untouched R13 (proven 179us).

#define NN     50000
#define HIDD   128
#define MAXD   16
#define NGRAPH 50
#define NCLSS  10
#define GRUH   32

typedef __attribute__((ext_vector_type(8))) short s16x8;    // 8 bf16 (4 VGPRs)
typedef __attribute__((ext_vector_type(4))) float f32x4;
typedef __hip_bfloat16 bf16;

#define MFMA16(a,b,c)  __builtin_amdgcn_mfma_f32_16x16x32_bf16((a),(b),(c),0,0,0)

__device__ __forceinline__ float bf2f(bf16 x) { return __bfloat162float(x); }
__device__ __forceinline__ bf16  f2bf(float x) { return __float2bfloat16(x); }
__device__ __forceinline__ s16x8 ldfrag(const bf16* p) { return *(const s16x8*)p; }

__device__ __forceinline__ s16x8 ldfrag_f32(const float* p) {
  const float4 a = *(const float4*)p;
  const float4 b = *(const float4*)(p + 4);
  union { s16x8 v; bf16 h[8]; } r;
  r.h[0] = f2bf(a.x); r.h[1] = f2bf(a.y); r.h[2] = f2bf(a.z); r.h[3] = f2bf(a.w);
  r.h[4] = f2bf(b.x); r.h[5] = f2bf(b.y); r.h[6] = f2bf(b.z); r.h[7] = f2bf(b.w);
  return r.v;
}

__device__ __forceinline__ float sigf(float x) {
  return __builtin_amdgcn_rcpf(1.0f + __expf(-x));
}
__device__ __forceinline__ float tanhf_(float x) {
  return 1.0f - 2.0f * __builtin_amdgcn_rcpf(1.0f + __expf(2.0f * x));
}

__device__ __forceinline__ unsigned packbf2(float a, float b) {
  union { bf16 h; unsigned short u; } x, y;
  x.h = f2bf(a); y.h = f2bf(b);
  return (unsigned)x.u | ((unsigned)y.u << 16);
}
__device__ __forceinline__ float lo2f(unsigned u) { return __uint_as_float(u << 16); }
__device__ __forceinline__ float hi2f(unsigned u) { return __uint_as_float(u & 0xffff0000u); }

// barrier that drains LDS ops only — global loads stay in flight
__device__ __forceinline__ void lgkm_barrier() {
  asm volatile("s_waitcnt lgkmcnt(0)\n\ts_barrier" ::: "memory");
}

// ---------------- prep: weight bf16 casts + transposes + bias fold ----------------
__global__ __launch_bounds__(256) void prep_kernel(const float* __restrict__ Wih,
                            const float* __restrict__ Whh, const float* __restrict__ bih,
                            const float* __restrict__ bhh, const float* __restrict__ Wself,
                            const float* __restrict__ Wneigh, const float* __restrict__ Wgc,
                            const float* __restrict__ Wgru,
                            bf16* WihB, bf16* WhhB, bf16* WsT, bf16* WnT,
                            bf16* WgT, bf16* WgruB, float* biasS) {
  const int total = 2 * 65536 + 3 * 16384 + 12288 + 512;   // 193024
  int stride = gridDim.x * blockDim.x;
  for (int idx = blockIdx.x * blockDim.x + threadIdx.x; idx < total; idx += stride) {
    int j = idx;
    if (j < 65536) { WihB[j] = f2bf(Wih[j]); continue; }
    j -= 65536;
    if (j < 65536) { WhhB[j] = f2bf(Whh[j]); continue; }
    j -= 65536;
    if (j < 16384) { int c = j >> 7, k = j & 127; WsT[j] = f2bf(Wself[k * HIDD + c]); continue; }
    j -= 16384;
    if (j < 16384) { int c = j >> 7, k = j & 127; WnT[j] = f2bf(Wneigh[k * HIDD + c]); continue; }
    j -= 16384;
    if (j < 16384) { int c = j >> 7, k = j & 127; WgT[j] = f2bf(Wgc[k * HIDD + c]); continue; }
    j -= 16384;
    if (j < 12288) { WgruB[j] = f2bf(Wgru[j]); continue; }
    j -= 12288;
    biasS[j] = bih[j] + bhh[j];
  }
}

// ---------------- counting sort by degree (DESCENDING): LDS hist ----------------
__global__ __launch_bounds__(256) void hist_kernel(const int* __restrict__ deg, int* hist) {
  __shared__ int lh[17];
  const int tid = threadIdx.x;
  if (tid < 17) lh[tid] = 0;
  __syncthreads();
  const int i = blockIdx.x * 256 + tid;
  if (i < NN) atomicAdd(&lh[deg[i]], 1);
  __syncthreads();
  if (tid < 17 && lh[tid]) atomicAdd(&hist[tid], lh[tid]);
}

__global__ __launch_bounds__(256) void scatter_kernel(const int* __restrict__ deg,
                                                      const int* __restrict__ hist,
                                                      int* __restrict__ resv,
                                                      int* __restrict__ perm) {
  __shared__ int lh[17], lbase[17], lpos[17];
  const int tid = threadIdx.x;
  if (tid < 17) { lh[tid] = 0; lpos[tid] = 0; }
  __syncthreads();
  const int i = blockIdx.x * 256 + tid;
  const int d = (i < NN) ? deg[i] : -1;
  if (d >= 0) atomicAdd(&lh[d], 1);
  __syncthreads();
  if (tid < 17) {
    int pre = 0;
    for (int k = tid + 1; k < 17; ++k) pre += hist[k];   // descending: larger degs first
    lbase[tid] = pre + (lh[tid] ? atomicAdd(&resv[tid], lh[tid]) : 0);
  }
  __syncthreads();
  if (d >= 0) {
    const int p = lbase[d] + atomicAdd(&lpos[d], 1);
    perm[p] = i;
  }
}

// ---------------- G-GEMM: G'[n][hcol*4+gate] = feat[n] @ Wih^T + bias ----------------
__global__ __launch_bounds__(256) void ggemm_kernel(const float* __restrict__ featF,
                                                    const bf16* __restrict__ WihB,
                                                    const float* __restrict__ biasS,
                                                    bf16* __restrict__ Gp) {
  const int lane = threadIdx.x & 63, wave = threadIdx.x >> 6;
  const int l15 = lane & 15, quad = lane >> 4;
  const int nb = blockIdx.x * 64;

  s16x8 Bx[4][4];
#pragma unroll
  for (int nt = 0; nt < 4; ++nt) {
    int arow = nb + nt * 16 + l15; if (arow >= NN) arow = NN - 1;
#pragma unroll
    for (int kt = 0; kt < 4; ++kt)
      Bx[nt][kt] = ldfrag_f32(featF + (size_t)arow * HIDD + kt * 32 + quad * 8);
  }

  for (int hg = wave * 8; hg < wave * 8 + 8; ++hg) {
    const int wr = (l15 & 3) * HIDD + hg * 4 + (l15 >> 2);
    s16x8 Aw[4];
#pragma unroll
    for (int kt = 0; kt < 4; ++kt)
      Aw[kt] = ldfrag(WihB + (size_t)wr * HIDD + kt * 32 + quad * 8);
    const int hcol = hg * 4 + quad;
    float b0 = biasS[0 * HIDD + hcol], b1 = biasS[1 * HIDD + hcol];
    float b2 = biasS[2 * HIDD + hcol], b3 = biasS[3 * HIDD + hcol];
#pragma unroll
    for (int nt = 0; nt < 4; ++nt) {
      f32x4 acc = {0.f, 0.f, 0.f, 0.f};
#pragma unroll
      for (int kt = 0; kt < 4; ++kt)
        acc = MFMA16(Aw[kt], Bx[nt][kt], acc);
      const int node = nb + nt * 16 + l15;
      if (node < NN) {
        unsigned u0 = packbf2(acc[0] + b0, acc[1] + b1);
        unsigned u1 = packbf2(acc[2] + b2, acc[3] + b3);
        *(uint2*)(Gp + (size_t)node * 512 + hcol * 4) = make_uint2(u0, u1);
      }
    }
  }
}

// ---------------- LSTM recurrence + fused SAGE epilogue ----------------
// 1024 thr / 16 waves / 64 nodes. Recurrence = R13-exact (h-part MFMA,
// x-gates gathered from G' at step top). Epilogue: final h rows are in LDS
// -> compute h1n = relu(feat@Ws + hT@Wn + b)*rsqrt(deg) right here.
// Epilogue mapping: wave w -> row-tile rq = w&3 (16 rows), col-pair
// cp = w>>2 (2 x 16 cols). A-frags loaded once per wave.
__global__ __launch_bounds__(1024, 4) void lstm_kernel(const bf16* __restrict__ Gp,
                                                       const bf16* __restrict__ WhhB,
                                                       const float* __restrict__ featF,
                                                       const bf16* __restrict__ WsT,
                                                       const bf16* __restrict__ WnT,
                                                       const float* __restrict__ b_sage,
                                                       const int* __restrict__ nbr_idx,
                                                       const int* __restrict__ deg,
                                                       const int* __restrict__ perm,
                                                       bf16* __restrict__ h1n) {
  __shared__ __align__(16) bf16 Hs[2][64 * 128];  // 32KB: h dbuf, oct-xor swizzled
  __shared__ int nbr_s[16 * 64];                  // [t][row]
  __shared__ int nodes_s[64];
  __shared__ int degs_s[64];

  const int tid = threadIdx.x;
  const int lane = tid & 63, w = tid >> 6;        // w = hcol-block 0..15
  const int l15 = lane & 15, quad = lane >> 4;
  const int base = blockIdx.x * 64;

  if (tid < 64) {
    const int gi = base + tid;
    const int nd = (gi < NN) ? perm[gi] : -1;
    nodes_s[tid] = nd;
    degs_s[tid] = (nd >= 0) ? deg[nd] : 0;
  }
  __syncthreads();
  {
    const int row = tid & 63, t = tid >> 6;       // exactly one entry per thread
    const int nd = nodes_s[row];
    nbr_s[t * 64 + row] = (nd >= 0) ? nbr_idx[nd * MAXD + t] : 0;
  }

  // pinned Whh packed frags: vrow v=l15 -> Whh row (v&3)*128 + w*8 + gt*4 + (v>>2)
  s16x8 Bh[2][4];
#pragma unroll
  for (int gt = 0; gt < 2; ++gt) {
    const int wr = (l15 & 3) * HIDD + w * 8 + gt * 4 + (l15 >> 2);
#pragma unroll
    for (int kt = 0; kt < 4; ++kt) {
      Bh[gt][kt] = ldfrag(WhhB + (size_t)wr * HIDD + kt * 32 + quad * 8);
      asm volatile("" : "+v"(Bh[gt][kt]));
    }
  }

  __syncthreads();                                // nbr_s visible
  const int maxdeg = degs_s[0];                   // descending sort -> block max

  int mydeg[4];
#pragma unroll
  for (int nt = 0; nt < 4; ++nt) mydeg[nt] = degs_s[nt * 16 + l15];

  // per-thread G' element offsets (col base = (w*8+gt*4+quad)*4)
  const int gofs0 = (w * 8 + 0 * 4 + quad) * 4;
  const int gofs1 = (w * 8 + 1 * 4 + quad) * 4;

  float cst[2][4] = {{0.f, 0.f, 0.f, 0.f}, {0.f, 0.f, 0.f, 0.f}};
  float hprev[2][4] = {{0.f, 0.f, 0.f, 0.f}, {0.f, 0.f, 0.f, 0.f}};

  for (int t = 0; t < maxdeg; ++t) {
    const int cur = t & 1, nxt = cur ^ 1;

    // gather x-gates for this step (consumed in cell; latency hidden by MFMA)
    uint2 gx[2][4];
#pragma unroll
    for (int nt = 0; nt < 4; ++nt) {
      const int nb1 = nbr_s[t * 64 + nt * 16 + l15];
      const bf16* gr = Gp + (size_t)nb1 * 512;
      gx[0][nt] = *(const uint2*)(gr + gofs0);
      gx[1][nt] = *(const uint2*)(gr + gofs1);
    }

    f32x4 acc[2][4];
#pragma unroll
    for (int gt = 0; gt < 2; ++gt)
#pragma unroll
      for (int nt = 0; nt < 4; ++nt) acc[gt][nt] = (f32x4){0.f, 0.f, 0.f, 0.f};

    // h-part: gates += Whh_packed @ h^T  (skip at t=0: h0 = 0)
    if (t > 0) {
#pragma unroll
      for (int kt = 0; kt < 4; ++kt) {
#pragma unroll
        for (int nt = 0; nt < 4; ++nt) {
          const int row = nt * 16 + l15;
          const s16x8 ah = ldfrag(Hs[cur] + row * 128 + (((kt * 4 + quad) ^ l15) * 8));
#pragma unroll
          for (int gt = 0; gt < 2; ++gt)
            acc[gt][nt] = MFMA16(Bh[gt][kt], ah, acc[gt][nt]);
        }
      }
    }

    // elementwise cell: lane's f32x4 = all 4 gates of one cell
#pragma unroll
    for (int gt = 0; gt < 2; ++gt) {
      const int col = w * 8 + gt * 4 + quad;
#pragma unroll
      for (int nt = 0; nt < 4; ++nt) {
        const int row = nt * 16 + l15;
        const uint2 g = gx[gt][nt];
        const float g_i = acc[gt][nt][0] + lo2f(g.x);
        const float g_f = acc[gt][nt][1] + hi2f(g.x);
        const float g_g = acc[gt][nt][2] + lo2f(g.y);
        const float g_o = acc[gt][nt][3] + hi2f(g.y);
        const float iv = sigf(g_i), fv = sigf(g_f);
        const float gv = tanhf_(g_g), ov = sigf(g_o);
        const float cn = fv * cst[gt][nt] + iv * gv;
        const float hn_new = ov * tanhf_(cn);
        const bool act = (t < mydeg[nt]);
        if (act) cst[gt][nt] = cn;
        const float hn = act ? hn_new : hprev[gt][nt];
        hprev[gt][nt] = hn;
        Hs[nxt][row * 128 + ((w ^ (row & 15)) * 8) + (col & 7)] = f2bf(hn);
      }
    }
    lgkm_barrier();   // single barrier: dbuf writes visible, reads done
  }

  // ---- fused SAGE epilogue: h1n = relu(feat@Ws + hT@Wn + b) * rsqrt(deg) ----
  const bf16* Hf = Hs[maxdeg & 1];
  {
    const int rq = w & 3, cp = w >> 2;
    const int rowA = rq * 16 + l15;               // A-frag row (m index)
    const int ndA = nodes_s[rowA];
    const int ndA2 = (ndA >= 0) ? ndA : 0;        // garbage rows never written
    s16x8 Fa[4], Ha[4];
#pragma unroll
    for (int kt = 0; kt < 4; ++kt) {
      Fa[kt] = ldfrag_f32(featF + (size_t)ndA2 * HIDD + kt * 32 + quad * 8);
      Ha[kt] = ldfrag(Hf + rowA * 128 + (((kt * 4 + quad) ^ l15) * 8));
    }
    int ndC[4]; float nrmC[4];
#pragma unroll
    for (int r = 0; r < 4; ++r) {
      const int rowC = rq * 16 + quad * 4 + r;
      ndC[r] = nodes_s[rowC];
      const int dd = degs_s[rowC];
      nrmC[r] = rsqrtf((float)((dd > 0) ? dd : 1));
    }
#pragma unroll
    for (int cc = 0; cc < 2; ++cc) {
      const int col = (cp * 2 + cc) * 16 + l15;
      f32x4 acc = {0.f, 0.f, 0.f, 0.f};
#pragma unroll
      for (int kt = 0; kt < 4; ++kt) {
        acc = MFMA16(Fa[kt], ldfrag(WsT + col * HIDD + kt * 32 + quad * 8), acc);
        acc = MFMA16(Ha[kt], ldfrag(WnT + col * HIDD + kt * 32 + quad * 8), acc);
      }
      const float bb = b_sage[col];
#pragma unroll
      for (int r = 0; r < 4; ++r)
        if (ndC[r] >= 0)
          h1n[(size_t)ndC[r] * HIDD + col] = f2bf(fmaxf(acc[r] + bb, 0.f) * nrmC[r]);
    }
  }
}

// ------- FUSED: agg gather -> gc GEMM -> GRU -> per-graph pool partial -------
// Block = 64 nodes (natural order). Phase A: NODE-PARALLEL gather — 4
// threads per node, 32 cols each, f32 reg accumulation, nbr lists in LDS.
// Phase B: h2 = relu(Ag @ W_gc + b) -> H2 (LDS); gru GEMM from H2.
// Phase C: gru outputs accumulate into <=2 per-graph LDS slots, one flush.
__global__ __launch_bounds__(256) void aggru_kernel(const bf16* __restrict__ h1n,
                                                    const int* __restrict__ nbr_idx,
                                                    const int* __restrict__ deg,
                                                    const int* __restrict__ gids,
                                                    const bf16* __restrict__ WgT,
                                                    const float* __restrict__ b_gc,
                                                    const bf16* __restrict__ WgruB,
                                                    const float* __restrict__ bih,
                                                    const float* __restrict__ bhh,
                                                    float* __restrict__ psums,
                                                    float* __restrict__ pcnts) {
  __shared__ __align__(16) bf16 Ag[64 * 136];     // aggregated rows, padded pitch
  __shared__ __align__(16) bf16 H2[64 * 136];     // h2 tile, padded pitch
  __shared__ int nbrL[64 * 16];                   // [node][t] nbr lists
  __shared__ float psl[2 * GRUH];
  __shared__ float pcl[2];
  const int tid = threadIdx.x;
  const int lane = tid & 63, wave = tid >> 6;
  const int l15 = lane & 15, quad = lane >> 4;
  const int nbb = blockIdx.x * 64;
  const int nb = nbb + wave * 16;

  if (tid < 2 * GRUH) psl[tid] = 0.f;
  if (tid < 2) pcl[tid] = 0.f;

  // stage nbr lists (contiguous copy)
  for (int e = tid; e < 64 * 16; e += 256) {
    const int node = nbb + (e >> 4);
    nbrL[e] = (node < NN) ? nbr_idx[node * MAXD + (e & 15)] : 0;
  }
  __syncthreads();

  // phase A: node-parallel gather. thread -> (node = tid>>2, cols (tid&3)*32..+31)
  {
    const int myn = tid >> 2;
    const int node = nbb + myn;
    const int seg = (tid & 3) * 32;
    const int d = (node < NN) ? deg[node] : 0;
    float accv[32];
#pragma unroll
    for (int k = 0; k < 32; ++k) accv[k] = 0.f;
#pragma unroll 2
    for (int j = 0; j < d; ++j) {
      const int nbr = nbrL[myn * 16 + j];
      const bf16* rp = h1n + (size_t)nbr * HIDD + seg;
#pragma unroll
      for (int f = 0; f < 4; ++f) {
        union { s16x8 v; unsigned u[4]; } t_;
        t_.v = ldfrag(rp + f * 8);
#pragma unroll
        for (int p = 0; p < 4; ++p) {
          accv[f * 8 + 2 * p]     += lo2f(t_.u[p]);
          accv[f * 8 + 2 * p + 1] += hi2f(t_.u[p]);
        }
      }
    }
    const float nm = (d > 0) ? rsqrtf((float)d) : 0.f;
#pragma unroll
    for (int f = 0; f < 4; ++f) {
      union { s16x8 v; bf16 h[8]; } o;
#pragma unroll
      for (int k = 0; k < 8; ++k) o.h[k] = f2bf(accv[f * 8 + k] * nm);
      *(s16x8*)(Ag + myn * 136 + seg + f * 8) = o.v;
    }
  }
  __syncthreads();

  // phase B1: gc GEMM from Ag; h2 = relu(.) -> H2
  s16x8 A[4];
#pragma unroll
  for (int kt = 0; kt < 4; ++kt)
    A[kt] = ldfrag(Ag + (wave * 16 + l15) * 136 + kt * 32 + quad * 8);
  for (int ct = 0; ct < 8; ++ct) {
    const int col = ct * 16 + l15;
    f32x4 acc = {0.f, 0.f, 0.f, 0.f};
#pragma unroll
    for (int kt = 0; kt < 4; ++kt)
      acc = MFMA16(A[kt], ldfrag(WgT + col * HIDD + kt * 32 + quad * 8), acc);
    const float bb = b_gc[col];
#pragma unroll
    for (int r = 0; r < 4; ++r)
      H2[(wave * 16 + quad * 4 + r) * 136 + col] = f2bf(fmaxf(acc[r] + bb, 0.f));
  }
  __syncthreads();

  // phase B2: gru GEMM over rows wave*16 + l15
  s16x8 A2[4];
#pragma unroll
  for (int kt = 0; kt < 4; ++kt)
    A2[kt] = ldfrag(H2 + (wave * 16 + l15) * 136 + kt * 32 + quad * 8);
  f32x4 acc[6];
#pragma unroll
  for (int ct = 0; ct < 6; ++ct) {
    f32x4 a = {0.f, 0.f, 0.f, 0.f};
#pragma unroll
    for (int kt = 0; kt < 4; ++kt)
      a = MFMA16(A2[kt], ldfrag(WgruB + (ct * 16 + l15) * HIDD + kt * 32 + quad * 8), a);
    acc[ct] = a;
  }

  // phase C: gru activation + per-graph accumulate (block spans <=2 graphs)
  const int g0 = gids[nbb];
  int mynode[4], mygs[4];
#pragma unroll
  for (int r = 0; r < 4; ++r) {
    const int nd = nb + quad * 4 + r;
    mynode[r] = nd;
    mygs[r] = (nd < NN) ? (gids[nd] - g0) : 0;
  }
#pragma unroll
  for (int u = 0; u < 2; ++u) {
    const int cu = 16 * u + l15;
    const float br = bih[cu] + bhh[cu];
    const float bz = bih[32 + cu] + bhh[32 + cu];
    const float bni = bih[64 + cu];
    const float bnh = bhh[64 + cu];
#pragma unroll
    for (int r = 0; r < 4; ++r) {
      if (mynode[r] < NN) {
        const float rv = sigf(acc[u][r] + br);
        const float zv = sigf(acc[2 + u][r] + bz);
        const float nv = tanhf_(acc[4 + u][r] + bni + rv * bnh);
        const float v = (1.f - zv) * nv;
        atomicAdd(&psl[mygs[r] * GRUH + cu], v);
        if (u == 0 && l15 == 0) atomicAdd(&pcl[mygs[r]], 1.f);
      }
    }
  }
  __syncthreads();
  if (tid < 2 * GRUH) {
    const int s = tid >> 5, c = tid & 31;
    const float vv = psl[tid];
    if (vv != 0.f && g0 + s < NGRAPH) atomicAdd(&psums[(g0 + s) * GRUH + c], vv);
  }
  if (tid < 2) {
    if (pcl[tid] != 0.f && g0 + tid < NGRAPH) atomicAdd(&pcnts[g0 + tid], pcl[tid]);
  }
}

// ------- final: per-graph mean + classifier -------
__global__ __launch_bounds__(256) void pool_final_kernel(const float* __restrict__ sums,
                                                         const float* __restrict__ cnts,
                                                         const float* __restrict__ Wcls,
                                                         const float* __restrict__ bcls,
                                                         float* __restrict__ out) {
  const int idx = blockIdx.x * blockDim.x + threadIdx.x;
  if (idx >= NGRAPH * NCLSS) return;
  const int g = idx / NCLSS, k = idx % NCLSS;
  const float inv = 1.0f / cnts[g];
  float acc = bcls[k];
#pragma unroll
  for (int cc = 0; cc < GRUH; ++cc)
    acc += sums[g * GRUH + cc] * inv * Wcls[cc * NCLSS + k];
  out[idx] = acc;
}

extern "C" void kernel_launch(void* const* d_in, const int* in_sizes, int n_in,
                              void* d_out, int out_size, void* d_ws, size_t ws_size,
                              hipStream_t stream) {
  const float* feature  = (const float*)d_in[0];
  const int*   nbr_idx  = (const int*)d_in[1];
  const int*   deg      = (const int*)d_in[2];
  const int*   gids     = (const int*)d_in[3];
  const float* lstm_Wih = (const float*)d_in[4];
  const float* lstm_Whh = (const float*)d_in[5];
  const float* lstm_bih = (const float*)d_in[6];
  const float* lstm_bhh = (const float*)d_in[7];
  const float* W_self   = (const float*)d_in[8];
  const float* W_neigh  = (const float*)d_in[9];
  const float* b_sage   = (const float*)d_in[10];
  const float* W_gc     = (const float*)d_in[11];
  const float* b_gc     = (const float*)d_in[12];
  const float* Wih_gru  = (const float*)d_in[13];
  const float* bih_gru  = (const float*)d_in[14];
  const float* bhh_gru  = (const float*)d_in[15];
  const float* W_cls    = (const float*)d_in[16];
  const float* b_cls    = (const float*)d_in[17];

  // workspace: peak 64.8 MB (within the 65.4 MB proven bound).
  // h1n at 0 (lstm-epilogue out, aggru in); Gp at 12.8M (dead after lstm).
  char* ws = (char*)d_ws;
  bf16*  h1nB  = (bf16*)(ws + 0);           // [NN,128] 12.8MB
  bf16*  Gp    = (bf16*)(ws + 12800000);    // [NN,512] 51.2MB (dead after lstm)
  const size_t wo = 64000000;
  bf16*  WihB  = (bf16*)(ws + wo);
  bf16*  WhhB  = (bf16*)(ws + wo + 131072);
  bf16*  WsT   = (bf16*)(ws + wo + 262144);
  bf16*  WnT   = (bf16*)(ws + wo + 294912);
  bf16*  WgT   = (bf16*)(ws + wo + 327680);
  bf16*  WgruB = (bf16*)(ws + wo + 360448);
  float* biasS = (float*)(ws + wo + 385024);
  int*   perm  = (int*)(ws + 64500000);
  int*   hist  = (int*)(ws + 64800000);     // [17]
  int*   resv  = hist + 17;                 // [17]
  float* psums = (float*)(ws + 64801216);   // [50][32]
  float* pcnts = psums + NGRAPH * GRUH;     // [50]

  prep_kernel<<<754, 256, 0, stream>>>(lstm_Wih, lstm_Whh, lstm_bih, lstm_bhh,
                                       W_self, W_neigh, W_gc, Wih_gru,
                                       WihB, WhhB, WsT, WnT, WgT, WgruB, biasS);
  hipMemsetAsync(hist, 0, 34 * sizeof(int), stream);
  hipMemsetAsync(psums, 0, (NGRAPH * GRUH + NGRAPH) * sizeof(float), stream);
  hist_kernel<<<196, 256, 0, stream>>>(deg, hist);
  scatter_kernel<<<196, 256, 0, stream>>>(deg, hist, resv, perm);
  ggemm_kernel<<<782, 256, 0, stream>>>(feature, WihB, biasS, Gp);
  lstm_kernel<<<782, 1024, 0, stream>>>(Gp, WhhB, feature, WsT, WnT, b_sage,
                                        nbr_idx, deg, perm, h1nB);
  aggru_kernel<<<782, 256, 0, stream>>>(h1nB, nbr_idx, deg, gids, WgT, b_gc,
                                        WgruB, bih_gru, bhh_gru, psums, pcnts);
  pool_final_kernel<<<2, 256, 0, stream>>>(psums, pcnts, W_cls, b_cls, (float*)d_out);
}

// Round 10
// 401.259 us; speedup vs baseline: 1.2863x; 1.0360x over previous
//
#include <hip/hip_runtime.h>
#include <hip/hip_bf16.h>

// GCN_71451075936314 on gfx950.
// R19: (a) ggemm store fix: old epilogue wrote 8B per lane at 1KB stride ->
//      every 64B line of the 51.2MB Gp written by 8 different instrs ->
//      L2-evict between partial writes -> RMW refetch (the ~100us gap in
//      the rest-side accounting). Now: MFMA epilogue -> LDS Gs[64][520]
//      (padded, 2-way-free banks), then contiguous coalesced 64KB write.
//      (b) memsets folded into prep (block 0 zeroes hist/resv/psums/pcnts).
//      (c) lstm: s_setprio(1) around h-MFMA cluster (T5; blocks at
//      different t give wave role-divergence).
//      R18 baseline: 415.7us total = lstm 212 + rest 204.

#define NN     50000
#define HIDD   128
#define MAXD   16
#define NGRAPH 50
#define NCLSS  10
#define GRUH   32

typedef __attribute__((ext_vector_type(8))) short s16x8;    // 8 bf16 (4 VGPRs)
typedef __attribute__((ext_vector_type(4))) float f32x4;
typedef __hip_bfloat16 bf16;

#define MFMA16(a,b,c)  __builtin_amdgcn_mfma_f32_16x16x32_bf16((a),(b),(c),0,0,0)

__device__ __forceinline__ float bf2f(bf16 x) { return __bfloat162float(x); }
__device__ __forceinline__ bf16  f2bf(float x) { return __float2bfloat16(x); }
__device__ __forceinline__ s16x8 ldfrag(const bf16* p) { return *(const s16x8*)p; }

__device__ __forceinline__ s16x8 ldfrag_f32(const float* p) {
  const float4 a = *(const float4*)p;
  const float4 b = *(const float4*)(p + 4);
  union { s16x8 v; bf16 h[8]; } r;
  r.h[0] = f2bf(a.x); r.h[1] = f2bf(a.y); r.h[2] = f2bf(a.z); r.h[3] = f2bf(a.w);
  r.h[4] = f2bf(b.x); r.h[5] = f2bf(b.y); r.h[6] = f2bf(b.z); r.h[7] = f2bf(b.w);
  return r.v;
}

__device__ __forceinline__ float sigf(float x) {
  return __builtin_amdgcn_rcpf(1.0f + __expf(-x));
}
__device__ __forceinline__ float tanhf_(float x) {
  return 1.0f - 2.0f * __builtin_amdgcn_rcpf(1.0f + __expf(2.0f * x));
}

__device__ __forceinline__ unsigned packbf2(float a, float b) {
  union { bf16 h; unsigned short u; } x, y;
  x.h = f2bf(a); y.h = f2bf(b);
  return (unsigned)x.u | ((unsigned)y.u << 16);
}
__device__ __forceinline__ float lo2f(unsigned u) { return __uint_as_float(u << 16); }
__device__ __forceinline__ float hi2f(unsigned u) { return __uint_as_float(u & 0xffff0000u); }

// barrier that drains LDS ops only — global loads stay in flight
__device__ __forceinline__ void lgkm_barrier() {
  asm volatile("s_waitcnt lgkmcnt(0)\n\ts_barrier" ::: "memory");
}

// ---------------- prep: weight bf16 casts + transposes + bias fold + zeroing ----------------
__global__ __launch_bounds__(256) void prep_kernel(const float* __restrict__ Wih,
                            const float* __restrict__ Whh, const float* __restrict__ bih,
                            const float* __restrict__ bhh, const float* __restrict__ Wself,
                            const float* __restrict__ Wneigh, const float* __restrict__ Wgc,
                            const float* __restrict__ Wgru,
                            bf16* WihB, bf16* WhhB, bf16* WsT, bf16* WnT,
                            bf16* WgT, bf16* WgruB, float* biasS,
                            int* hist, float* psums) {
  if (blockIdx.x == 0) {                       // fold the old memsets in
    for (int i = threadIdx.x; i < 34; i += 256) hist[i] = 0;           // hist+resv
    for (int i = threadIdx.x; i < NGRAPH * GRUH + NGRAPH; i += 256) psums[i] = 0.f;
  }
  const int total = 2 * 65536 + 3 * 16384 + 12288 + 512;   // 193024
  int stride = gridDim.x * blockDim.x;
  for (int idx = blockIdx.x * blockDim.x + threadIdx.x; idx < total; idx += stride) {
    int j = idx;
    if (j < 65536) { WihB[j] = f2bf(Wih[j]); continue; }
    j -= 65536;
    if (j < 65536) { WhhB[j] = f2bf(Whh[j]); continue; }
    j -= 65536;
    if (j < 16384) { int c = j >> 7, k = j & 127; WsT[j] = f2bf(Wself[k * HIDD + c]); continue; }
    j -= 16384;
    if (j < 16384) { int c = j >> 7, k = j & 127; WnT[j] = f2bf(Wneigh[k * HIDD + c]); continue; }
    j -= 16384;
    if (j < 16384) { int c = j >> 7, k = j & 127; WgT[j] = f2bf(Wgc[k * HIDD + c]); continue; }
    j -= 16384;
    if (j < 12288) { WgruB[j] = f2bf(Wgru[j]); continue; }
    j -= 12288;
    biasS[j] = bih[j] + bhh[j];
  }
}

// ---------------- counting sort by degree (DESCENDING): LDS hist ----------------
__global__ __launch_bounds__(256) void hist_kernel(const int* __restrict__ deg, int* hist) {
  __shared__ int lh[17];
  const int tid = threadIdx.x;
  if (tid < 17) lh[tid] = 0;
  __syncthreads();
  const int i = blockIdx.x * 256 + tid;
  if (i < NN) atomicAdd(&lh[deg[i]], 1);
  __syncthreads();
  if (tid < 17 && lh[tid]) atomicAdd(&hist[tid], lh[tid]);
}

__global__ __launch_bounds__(256) void scatter_kernel(const int* __restrict__ deg,
                                                      const int* __restrict__ hist,
                                                      int* __restrict__ resv,
                                                      int* __restrict__ perm) {
  __shared__ int lh[17], lbase[17], lpos[17];
  const int tid = threadIdx.x;
  if (tid < 17) { lh[tid] = 0; lpos[tid] = 0; }
  __syncthreads();
  const int i = blockIdx.x * 256 + tid;
  const int d = (i < NN) ? deg[i] : -1;
  if (d >= 0) atomicAdd(&lh[d], 1);
  __syncthreads();
  if (tid < 17) {
    int pre = 0;
    for (int k = tid + 1; k < 17; ++k) pre += hist[k];   // descending: larger degs first
    lbase[tid] = pre + (lh[tid] ? atomicAdd(&resv[tid], lh[tid]) : 0);
  }
  __syncthreads();
  if (d >= 0) {
    const int p = lbase[d] + atomicAdd(&lpos[d], 1);
    perm[p] = i;
  }
}

// ---------------- G-GEMM: G'[n][hcol*4+gate] = feat[n] @ Wih^T + bias ----------------
// MFMA epilogue -> LDS Gs (padded rows), then coalesced contiguous write to
// Gp. (Old path: 8B stores at 1KB stride -> partial-line RMW on 51.2MB.)
__global__ __launch_bounds__(256) void ggemm_kernel(const float* __restrict__ featF,
                                                    const bf16* __restrict__ WihB,
                                                    const float* __restrict__ biasS,
                                                    bf16* __restrict__ Gp) {
  __shared__ __align__(16) bf16 Gs[64][520];    // 66.6KB, pad 520 -> 2-way banks
  const int lane = threadIdx.x & 63, wave = threadIdx.x >> 6;
  const int l15 = lane & 15, quad = lane >> 4;
  const int nb = blockIdx.x * 64;

  s16x8 Bx[4][4];
#pragma unroll
  for (int nt = 0; nt < 4; ++nt) {
    int arow = nb + nt * 16 + l15; if (arow >= NN) arow = NN - 1;
#pragma unroll
    for (int kt = 0; kt < 4; ++kt)
      Bx[nt][kt] = ldfrag_f32(featF + (size_t)arow * HIDD + kt * 32 + quad * 8);
  }

  for (int hg = wave * 8; hg < wave * 8 + 8; ++hg) {
    const int wr = (l15 & 3) * HIDD + hg * 4 + (l15 >> 2);
    s16x8 Aw[4];
#pragma unroll
    for (int kt = 0; kt < 4; ++kt)
      Aw[kt] = ldfrag(WihB + (size_t)wr * HIDD + kt * 32 + quad * 8);
    const int hcol = hg * 4 + quad;
    float b0 = biasS[0 * HIDD + hcol], b1 = biasS[1 * HIDD + hcol];
    float b2 = biasS[2 * HIDD + hcol], b3 = biasS[3 * HIDD + hcol];
#pragma unroll
    for (int nt = 0; nt < 4; ++nt) {
      f32x4 acc = {0.f, 0.f, 0.f, 0.f};
#pragma unroll
      for (int kt = 0; kt < 4; ++kt)
        acc = MFMA16(Aw[kt], Bx[nt][kt], acc);
      unsigned u0 = packbf2(acc[0] + b0, acc[1] + b1);
      unsigned u1 = packbf2(acc[2] + b2, acc[3] + b3);
      *(uint2*)(&Gs[nt * 16 + l15][hcol * 4]) = make_uint2(u0, u1);
    }
  }
  __syncthreads();
  // coalesced write-out: 4096 chunks of 8 els; consecutive lanes = contiguous 16B
  const int tid = threadIdx.x;
  for (int e = tid; e < 4096; e += 256) {
    const int r = e >> 6, off = (e & 63) * 8;
    const int node = nb + r;
    if (node < NN)
      *(s16x8*)(Gp + (size_t)node * 512 + off) = *(const s16x8*)(&Gs[r][off]);
  }
}

// ---------------- LSTM recurrence + fused SAGE epilogue ----------------
// 1024 thr / 16 waves / 64 nodes. Recurrence = R13-exact (h-part MFMA,
// x-gates gathered from G' at step top) + setprio around the MFMA cluster.
__global__ __launch_bounds__(1024, 4) void lstm_kernel(const bf16* __restrict__ Gp,
                                                       const bf16* __restrict__ WhhB,
                                                       const float* __restrict__ featF,
                                                       const bf16* __restrict__ WsT,
                                                       const bf16* __restrict__ WnT,
                                                       const float* __restrict__ b_sage,
                                                       const int* __restrict__ nbr_idx,
                                                       const int* __restrict__ deg,
                                                       const int* __restrict__ perm,
                                                       bf16* __restrict__ h1n) {
  __shared__ __align__(16) bf16 Hs[2][64 * 128];  // 32KB: h dbuf, oct-xor swizzled
  __shared__ int nbr_s[16 * 64];                  // [t][row]
  __shared__ int nodes_s[64];
  __shared__ int degs_s[64];

  const int tid = threadIdx.x;
  const int lane = tid & 63, w = tid >> 6;        // w = hcol-block 0..15
  const int l15 = lane & 15, quad = lane >> 4;
  const int base = blockIdx.x * 64;

  if (tid < 64) {
    const int gi = base + tid;
    const int nd = (gi < NN) ? perm[gi] : -1;
    nodes_s[tid] = nd;
    degs_s[tid] = (nd >= 0) ? deg[nd] : 0;
  }
  __syncthreads();
  {
    const int row = tid & 63, t = tid >> 6;       // exactly one entry per thread
    const int nd = nodes_s[row];
    nbr_s[t * 64 + row] = (nd >= 0) ? nbr_idx[nd * MAXD + t] : 0;
  }

  // pinned Whh packed frags: vrow v=l15 -> Whh row (v&3)*128 + w*8 + gt*4 + (v>>2)
  s16x8 Bh[2][4];
#pragma unroll
  for (int gt = 0; gt < 2; ++gt) {
    const int wr = (l15 & 3) * HIDD + w * 8 + gt * 4 + (l15 >> 2);
#pragma unroll
    for (int kt = 0; kt < 4; ++kt) {
      Bh[gt][kt] = ldfrag(WhhB + (size_t)wr * HIDD + kt * 32 + quad * 8);
      asm volatile("" : "+v"(Bh[gt][kt]));
    }
  }

  __syncthreads();                                // nbr_s visible
  const int maxdeg = degs_s[0];                   // descending sort -> block max

  int mydeg[4];
#pragma unroll
  for (int nt = 0; nt < 4; ++nt) mydeg[nt] = degs_s[nt * 16 + l15];

  // per-thread G' element offsets (col base = (w*8+gt*4+quad)*4)
  const int gofs0 = (w * 8 + 0 * 4 + quad) * 4;
  const int gofs1 = (w * 8 + 1 * 4 + quad) * 4;

  float cst[2][4] = {{0.f, 0.f, 0.f, 0.f}, {0.f, 0.f, 0.f, 0.f}};
  float hprev[2][4] = {{0.f, 0.f, 0.f, 0.f}, {0.f, 0.f, 0.f, 0.f}};

  for (int t = 0; t < maxdeg; ++t) {
    const int cur = t & 1, nxt = cur ^ 1;

    // gather x-gates for this step (consumed in cell; latency hidden by MFMA)
    uint2 gx[2][4];
#pragma unroll
    for (int nt = 0; nt < 4; ++nt) {
      const int nb1 = nbr_s[t * 64 + nt * 16 + l15];
      const bf16* gr = Gp + (size_t)nb1 * 512;
      gx[0][nt] = *(const uint2*)(gr + gofs0);
      gx[1][nt] = *(const uint2*)(gr + gofs1);
    }

    f32x4 acc[2][4];
#pragma unroll
    for (int gt = 0; gt < 2; ++gt)
#pragma unroll
      for (int nt = 0; nt < 4; ++nt) acc[gt][nt] = (f32x4){0.f, 0.f, 0.f, 0.f};

    // h-part: gates += Whh_packed @ h^T  (skip at t=0: h0 = 0)
    if (t > 0) {
      __builtin_amdgcn_s_setprio(1);
#pragma unroll
      for (int kt = 0; kt < 4; ++kt) {
#pragma unroll
        for (int nt = 0; nt < 4; ++nt) {
          const int row = nt * 16 + l15;
          const s16x8 ah = ldfrag(Hs[cur] + row * 128 + (((kt * 4 + quad) ^ l15) * 8));
#pragma unroll
          for (int gt = 0; gt < 2; ++gt)
            acc[gt][nt] = MFMA16(Bh[gt][kt], ah, acc[gt][nt]);
        }
      }
      __builtin_amdgcn_s_setprio(0);
    }

    // elementwise cell: lane's f32x4 = all 4 gates of one cell
#pragma unroll
    for (int gt = 0; gt < 2; ++gt) {
      const int col = w * 8 + gt * 4 + quad;
#pragma unroll
      for (int nt = 0; nt < 4; ++nt) {
        const int row = nt * 16 + l15;
        const uint2 g = gx[gt][nt];
        const float g_i = acc[gt][nt][0] + lo2f(g.x);
        const float g_f = acc[gt][nt][1] + hi2f(g.x);
        const float g_g = acc[gt][nt][2] + lo2f(g.y);
        const float g_o = acc[gt][nt][3] + hi2f(g.y);
        const float iv = sigf(g_i), fv = sigf(g_f);
        const float gv = tanhf_(g_g), ov = sigf(g_o);
        const float cn = fv * cst[gt][nt] + iv * gv;
        const float hn_new = ov * tanhf_(cn);
        const bool act = (t < mydeg[nt]);
        if (act) cst[gt][nt] = cn;
        const float hn = act ? hn_new : hprev[gt][nt];
        hprev[gt][nt] = hn;
        Hs[nxt][row * 128 + ((w ^ (row & 15)) * 8) + (col & 7)] = f2bf(hn);
      }
    }
    lgkm_barrier();   // single barrier: dbuf writes visible, reads done
  }

  // ---- fused SAGE epilogue: h1n = relu(feat@Ws + hT@Wn + b) * rsqrt(deg) ----
  const bf16* Hf = Hs[maxdeg & 1];
  {
    const int rq = w & 3, cp = w >> 2;
    const int rowA = rq * 16 + l15;               // A-frag row (m index)
    const int ndA = nodes_s[rowA];
    const int ndA2 = (ndA >= 0) ? ndA : 0;        // garbage rows never written
    s16x8 Fa[4], Ha[4];
#pragma unroll
    for (int kt = 0; kt < 4; ++kt) {
      Fa[kt] = ldfrag_f32(featF + (size_t)ndA2 * HIDD + kt * 32 + quad * 8);
      Ha[kt] = ldfrag(Hf + rowA * 128 + (((kt * 4 + quad) ^ l15) * 8));
    }
    int ndC[4]; float nrmC[4];
#pragma unroll
    for (int r = 0; r < 4; ++r) {
      const int rowC = rq * 16 + quad * 4 + r;
      ndC[r] = nodes_s[rowC];
      const int dd = degs_s[rowC];
      nrmC[r] = rsqrtf((float)((dd > 0) ? dd : 1));
    }
#pragma unroll
    for (int cc = 0; cc < 2; ++cc) {
      const int col = (cp * 2 + cc) * 16 + l15;
      f32x4 acc = {0.f, 0.f, 0.f, 0.f};
#pragma unroll
      for (int kt = 0; kt < 4; ++kt) {
        acc = MFMA16(Fa[kt], ldfrag(WsT + col * HIDD + kt * 32 + quad * 8), acc);
        acc = MFMA16(Ha[kt], ldfrag(WnT + col * HIDD + kt * 32 + quad * 8), acc);
      }
      const float bb = b_sage[col];
#pragma unroll
      for (int r = 0; r < 4; ++r)
        if (ndC[r] >= 0)
          h1n[(size_t)ndC[r] * HIDD + col] = f2bf(fmaxf(acc[r] + bb, 0.f) * nrmC[r]);
    }
  }
}

// ------- FUSED: agg gather -> gc GEMM -> GRU -> per-graph pool partial -------
__global__ __launch_bounds__(256) void aggru_kernel(const bf16* __restrict__ h1n,
                                                    const int* __restrict__ nbr_idx,
                                                    const int* __restrict__ deg,
                                                    const int* __restrict__ gids,
                                                    const bf16* __restrict__ WgT,
                                                    const float* __restrict__ b_gc,
                                                    const bf16* __restrict__ WgruB,
                                                    const float* __restrict__ bih,
                                                    const float* __restrict__ bhh,
                                                    float* __restrict__ psums,
                                                    float* __restrict__ pcnts) {
  __shared__ __align__(16) bf16 Ag[64 * 136];     // aggregated rows, padded pitch
  __shared__ __align__(16) bf16 H2[64 * 136];     // h2 tile, padded pitch
  __shared__ int nbrL[64 * 16];                   // [node][t] nbr lists
  __shared__ float psl[2 * GRUH];
  __shared__ float pcl[2];
  const int tid = threadIdx.x;
  const int lane = tid & 63, wave = tid >> 6;
  const int l15 = lane & 15, quad = lane >> 4;
  const int nbb = blockIdx.x * 64;
  const int nb = nbb + wave * 16;

  if (tid < 2 * GRUH) psl[tid] = 0.f;
  if (tid < 2) pcl[tid] = 0.f;

  // stage nbr lists (contiguous copy)
  for (int e = tid; e < 64 * 16; e += 256) {
    const int node = nbb + (e >> 4);
    nbrL[e] = (node < NN) ? nbr_idx[node * MAXD + (e & 15)] : 0;
  }
  __syncthreads();

  // phase A: node-parallel gather. thread -> (node = tid>>2, cols (tid&3)*32..+31)
  {
    const int myn = tid >> 2;
    const int node = nbb + myn;
    const int seg = (tid & 3) * 32;
    const int d = (node < NN) ? deg[node] : 0;
    float accv[32];
#pragma unroll
    for (int k = 0; k < 32; ++k) accv[k] = 0.f;
#pragma unroll 2
    for (int j = 0; j < d; ++j) {
      const int nbr = nbrL[myn * 16 + j];
      const bf16* rp = h1n + (size_t)nbr * HIDD + seg;
#pragma unroll
      for (int f = 0; f < 4; ++f) {
        union { s16x8 v; unsigned u[4]; } t_;
        t_.v = ldfrag(rp + f * 8);
#pragma unroll
        for (int p = 0; p < 4; ++p) {
          accv[f * 8 + 2 * p]     += lo2f(t_.u[p]);
          accv[f * 8 + 2 * p + 1] += hi2f(t_.u[p]);
        }
      }
    }
    const float nm = (d > 0) ? rsqrtf((float)d) : 0.f;
#pragma unroll
    for (int f = 0; f < 4; ++f) {
      union { s16x8 v; bf16 h[8]; } o;
#pragma unroll
      for (int k = 0; k < 8; ++k) o.h[k] = f2bf(accv[f * 8 + k] * nm);
      *(s16x8*)(Ag + myn * 136 + seg + f * 8) = o.v;
    }
  }
  __syncthreads();

  // phase B1: gc GEMM from Ag; h2 = relu(.) -> H2
  s16x8 A[4];
#pragma unroll
  for (int kt = 0; kt < 4; ++kt)
    A[kt] = ldfrag(Ag + (wave * 16 + l15) * 136 + kt * 32 + quad * 8);
  for (int ct = 0; ct < 8; ++ct) {
    const int col = ct * 16 + l15;
    f32x4 acc = {0.f, 0.f, 0.f, 0.f};
#pragma unroll
    for (int kt = 0; kt < 4; ++kt)
      acc = MFMA16(A[kt], ldfrag(WgT + col * HIDD + kt * 32 + quad * 8), acc);
    const float bb = b_gc[col];
#pragma unroll
    for (int r = 0; r < 4; ++r)
      H2[(wave * 16 + quad * 4 + r) * 136 + col] = f2bf(fmaxf(acc[r] + bb, 0.f));
  }
  __syncthreads();

  // phase B2: gru GEMM over rows wave*16 + l15
  s16x8 A2[4];
#pragma unroll
  for (int kt = 0; kt < 4; ++kt)
    A2[kt] = ldfrag(H2 + (wave * 16 + l15) * 136 + kt * 32 + quad * 8);
  f32x4 acc[6];
#pragma unroll
  for (int ct = 0; ct < 6; ++ct) {
    f32x4 a = {0.f, 0.f, 0.f, 0.f};
#pragma unroll
    for (int kt = 0; kt < 4; ++kt)
      a = MFMA16(A2[kt], ldfrag(WgruB + (ct * 16 + l15) * HIDD + kt * 32 + quad * 8), a);
    acc[ct] = a;
  }

  // phase C: gru activation + per-graph accumulate (block spans <=2 graphs)
  const int g0 = gids[nbb];
  int mynode[4], mygs[4];
#pragma unroll
  for (int r = 0; r < 4; ++r) {
    const int nd = nb + quad * 4 + r;
    mynode[r] = nd;
    mygs[r] = (nd < NN) ? (gids[nd] - g0) : 0;
  }
#pragma unroll
  for (int u = 0; u < 2; ++u) {
    const int cu = 16 * u + l15;
    const float br = bih[cu] + bhh[cu];
    const float bz = bih[32 + cu] + bhh[32 + cu];
    const float bni = bih[64 + cu];
    const float bnh = bhh[64 + cu];
#pragma unroll
    for (int r = 0; r < 4; ++r) {
      if (mynode[r] < NN) {
        const float rv = sigf(acc[u][r] + br);
        const float zv = sigf(acc[2 + u][r] + bz);
        const float nv = tanhf_(acc[4 + u][r] + bni + rv * bnh);
        const float v = (1.f - zv) * nv;
        atomicAdd(&psl[mygs[r] * GRUH + cu], v);
        if (u == 0 && l15 == 0) atomicAdd(&pcl[mygs[r]], 1.f);
      }
    }
  }
  __syncthreads();
  if (tid < 2 * GRUH) {
    const int s = tid >> 5, c = tid & 31;
    const float vv = psl[tid];
    if (vv != 0.f && g0 + s < NGRAPH) atomicAdd(&psums[(g0 + s) * GRUH + c], vv);
  }
  if (tid < 2) {
    if (pcl[tid] != 0.f && g0 + tid < NGRAPH) atomicAdd(&pcnts[g0 + tid], pcl[tid]);
  }
}

// ------- final: per-graph mean + classifier -------
__global__ __launch_bounds__(256) void pool_final_kernel(const float* __restrict__ sums,
                                                         const float* __restrict__ cnts,
                                                         const float* __restrict__ Wcls,
                                                         const float* __restrict__ bcls,
                                                         float* __restrict__ out) {
  const int idx = blockIdx.x * blockDim.x + threadIdx.x;
  if (idx >= NGRAPH * NCLSS) return;
  const int g = idx / NCLSS, k = idx % NCLSS;
  const float inv = 1.0f / cnts[g];
  float acc = bcls[k];
#pragma unroll
  for (int cc = 0; cc < GRUH; ++cc)
    acc += sums[g * GRUH + cc] * inv * Wcls[cc * NCLSS + k];
  out[idx] = acc;
}

extern "C" void kernel_launch(void* const* d_in, const int* in_sizes, int n_in,
                              void* d_out, int out_size, void* d_ws, size_t ws_size,
                              hipStream_t stream) {
  const float* feature  = (const float*)d_in[0];
  const int*   nbr_idx  = (const int*)d_in[1];
  const int*   deg      = (const int*)d_in[2];
  const int*   gids     = (const int*)d_in[3];
  const float* lstm_Wih = (const float*)d_in[4];
  const float* lstm_Whh = (const float*)d_in[5];
  const float* lstm_bih = (const float*)d_in[6];
  const float* lstm_bhh = (const float*)d_in[7];
  const float* W_self   = (const float*)d_in[8];
  const float* W_neigh  = (const float*)d_in[9];
  const float* b_sage   = (const float*)d_in[10];
  const float* W_gc     = (const float*)d_in[11];
  const float* b_gc     = (const float*)d_in[12];
  const float* Wih_gru  = (const float*)d_in[13];
  const float* bih_gru  = (const float*)d_in[14];
  const float* bhh_gru  = (const float*)d_in[15];
  const float* W_cls    = (const float*)d_in[16];
  const float* b_cls    = (const float*)d_in[17];

  // workspace: peak 64.8 MB (within the 65.4 MB proven bound).
  // h1n at 0 (lstm-epilogue out, aggru in); Gp at 12.8M (dead after lstm).
  char* ws = (char*)d_ws;
  bf16*  h1nB  = (bf16*)(ws + 0);           // [NN,128] 12.8MB
  bf16*  Gp    = (bf16*)(ws + 12800000);    // [NN,512] 51.2MB (dead after lstm)
  const size_t wo = 64000000;
  bf16*  WihB  = (bf16*)(ws + wo);
  bf16*  WhhB  = (bf16*)(ws + wo + 131072);
  bf16*  WsT   = (bf16*)(ws + wo + 262144);
  bf16*  WnT   = (bf16*)(ws + wo + 294912);
  bf16*  WgT   = (bf16*)(ws + wo + 327680);
  bf16*  WgruB = (bf16*)(ws + wo + 360448);
  float* biasS = (float*)(ws + wo + 385024);
  int*   perm  = (int*)(ws + 64500000);
  int*   hist  = (int*)(ws + 64800000);     // [17] + resv [17]
  int*   resv  = hist + 17;
  float* psums = (float*)(ws + 64801216);   // [50][32] + pcnts [50]
  float* pcnts = psums + NGRAPH * GRUH;

  prep_kernel<<<754, 256, 0, stream>>>(lstm_Wih, lstm_Whh, lstm_bih, lstm_bhh,
                                       W_self, W_neigh, W_gc, Wih_gru,
                                       WihB, WhhB, WsT, WnT, WgT, WgruB, biasS,
                                       hist, psums);
  hist_kernel<<<196, 256, 0, stream>>>(deg, hist);
  scatter_kernel<<<196, 256, 0, stream>>>(deg, hist, resv, perm);
  ggemm_kernel<<<782, 256, 0, stream>>>(feature, WihB, biasS, Gp);
  lstm_kernel<<<782, 1024, 0, stream>>>(Gp, WhhB, feature, WsT, WnT, b_sage,
                                        nbr_idx, deg, perm, h1nB);
  aggru_kernel<<<782, 256, 0, stream>>>(h1nB, nbr_idx, deg, gids, WgT, b_gc,
                                        WgruB, bih_gru, bhh_gru, psums, pcnts);
  pool_final_kernel<<<2, 256, 0, stream>>>(psums, pcnts, W_cls, b_cls, (float*)d_out);
}

// Round 11
// 378.940 us; speedup vs baseline: 1.3620x; 1.0589x over previous
//
#include <hip/hip_runtime.h>
#include <hip/hip_bf16.h>

// GCN_71451075936314 on gfx950.
// R20: two fixes on R19 (401.3us = lstm 214 + rest 187).
//      (a) ggemm: R19's Gs[64][520] = 133KB LDS -> 1 block/CU (4 waves!)
//          for a 77MB-moving kernel. Now 2 passes x Gs[32][520] = 33KB ->
//          4 blocks/CU. Weight A-frags re-read per pass (L2-resident).
//      (b) G' repack: new_off = w*32 + quad*8 + gt*4 + gate makes each
//          lstm thread's two gate-chunks ADJACENT -> gather is 4 x 16B
//          instead of 8 x 8B per thread per step (half the VMEM issue
//          slots in the latency-bound chain). Same 64B-line efficiency.
//          Writer (ggemm) + reader (lstm) updated consistently.

#define NN     50000
#define HIDD   128
#define MAXD   16
#define NGRAPH 50
#define NCLSS  10
#define GRUH   32

typedef __attribute__((ext_vector_type(8))) short s16x8;    // 8 bf16 (4 VGPRs)
typedef __attribute__((ext_vector_type(4))) float f32x4;
typedef __hip_bfloat16 bf16;

#define MFMA16(a,b,c)  __builtin_amdgcn_mfma_f32_16x16x32_bf16((a),(b),(c),0,0,0)

__device__ __forceinline__ float bf2f(bf16 x) { return __bfloat162float(x); }
__device__ __forceinline__ bf16  f2bf(float x) { return __float2bfloat16(x); }
__device__ __forceinline__ s16x8 ldfrag(const bf16* p) { return *(const s16x8*)p; }

__device__ __forceinline__ s16x8 ldfrag_f32(const float* p) {
  const float4 a = *(const float4*)p;
  const float4 b = *(const float4*)(p + 4);
  union { s16x8 v; bf16 h[8]; } r;
  r.h[0] = f2bf(a.x); r.h[1] = f2bf(a.y); r.h[2] = f2bf(a.z); r.h[3] = f2bf(a.w);
  r.h[4] = f2bf(b.x); r.h[5] = f2bf(b.y); r.h[6] = f2bf(b.z); r.h[7] = f2bf(b.w);
  return r.v;
}

__device__ __forceinline__ float sigf(float x) {
  return __builtin_amdgcn_rcpf(1.0f + __expf(-x));
}
__device__ __forceinline__ float tanhf_(float x) {
  return 1.0f - 2.0f * __builtin_amdgcn_rcpf(1.0f + __expf(2.0f * x));
}

__device__ __forceinline__ unsigned packbf2(float a, float b) {
  union { bf16 h; unsigned short u; } x, y;
  x.h = f2bf(a); y.h = f2bf(b);
  return (unsigned)x.u | ((unsigned)y.u << 16);
}
__device__ __forceinline__ float lo2f(unsigned u) { return __uint_as_float(u << 16); }
__device__ __forceinline__ float hi2f(unsigned u) { return __uint_as_float(u & 0xffff0000u); }

// barrier that drains LDS ops only — global loads stay in flight
__device__ __forceinline__ void lgkm_barrier() {
  asm volatile("s_waitcnt lgkmcnt(0)\n\ts_barrier" ::: "memory");
}

// ---------------- prep: weight bf16 casts + transposes + bias fold + zeroing ----------------
__global__ __launch_bounds__(256) void prep_kernel(const float* __restrict__ Wih,
                            const float* __restrict__ Whh, const float* __restrict__ bih,
                            const float* __restrict__ bhh, const float* __restrict__ Wself,
                            const float* __restrict__ Wneigh, const float* __restrict__ Wgc,
                            const float* __restrict__ Wgru,
                            bf16* WihB, bf16* WhhB, bf16* WsT, bf16* WnT,
                            bf16* WgT, bf16* WgruB, float* biasS,
                            int* hist, float* psums) {
  if (blockIdx.x == 0) {                       // fold the old memsets in
    for (int i = threadIdx.x; i < 34; i += 256) hist[i] = 0;           // hist+resv
    for (int i = threadIdx.x; i < NGRAPH * GRUH + NGRAPH; i += 256) psums[i] = 0.f;
  }
  const int total = 2 * 65536 + 3 * 16384 + 12288 + 512;   // 193024
  int stride = gridDim.x * blockDim.x;
  for (int idx = blockIdx.x * blockDim.x + threadIdx.x; idx < total; idx += stride) {
    int j = idx;
    if (j < 65536) { WihB[j] = f2bf(Wih[j]); continue; }
    j -= 65536;
    if (j < 65536) { WhhB[j] = f2bf(Whh[j]); continue; }
    j -= 65536;
    if (j < 16384) { int c = j >> 7, k = j & 127; WsT[j] = f2bf(Wself[k * HIDD + c]); continue; }
    j -= 16384;
    if (j < 16384) { int c = j >> 7, k = j & 127; WnT[j] = f2bf(Wneigh[k * HIDD + c]); continue; }
    j -= 16384;
    if (j < 16384) { int c = j >> 7, k = j & 127; WgT[j] = f2bf(Wgc[k * HIDD + c]); continue; }
    j -= 16384;
    if (j < 12288) { WgruB[j] = f2bf(Wgru[j]); continue; }
    j -= 12288;
    biasS[j] = bih[j] + bhh[j];
  }
}

// ---------------- counting sort by degree (DESCENDING): LDS hist ----------------
__global__ __launch_bounds__(256) void hist_kernel(const int* __restrict__ deg, int* hist) {
  __shared__ int lh[17];
  const int tid = threadIdx.x;
  if (tid < 17) lh[tid] = 0;
  __syncthreads();
  const int i = blockIdx.x * 256 + tid;
  if (i < NN) atomicAdd(&lh[deg[i]], 1);
  __syncthreads();
  if (tid < 17 && lh[tid]) atomicAdd(&hist[tid], lh[tid]);
}

__global__ __launch_bounds__(256) void scatter_kernel(const int* __restrict__ deg,
                                                      const int* __restrict__ hist,
                                                      int* __restrict__ resv,
                                                      int* __restrict__ perm) {
  __shared__ int lh[17], lbase[17], lpos[17];
  const int tid = threadIdx.x;
  if (tid < 17) { lh[tid] = 0; lpos[tid] = 0; }
  __syncthreads();
  const int i = blockIdx.x * 256 + tid;
  const int d = (i < NN) ? deg[i] : -1;
  if (d >= 0) atomicAdd(&lh[d], 1);
  __syncthreads();
  if (tid < 17) {
    int pre = 0;
    for (int k = tid + 1; k < 17; ++k) pre += hist[k];   // descending: larger degs first
    lbase[tid] = pre + (lh[tid] ? atomicAdd(&resv[tid], lh[tid]) : 0);
  }
  __syncthreads();
  if (d >= 0) {
    const int p = lbase[d] + atomicAdd(&lpos[d], 1);
    perm[p] = i;
  }
}

// ---------------- G-GEMM: G''[n][w*32+quad*8+gt*4+gate] = feat[n]@Wih^T + bias ----------------
// Two passes of 32 rows through LDS (33KB -> 4 blocks/CU), then coalesced
// contiguous write. Layout packs each lstm thread's (gt0,gt1) chunks
// adjacent so the lstm gather is one 16B load per node.
__global__ __launch_bounds__(256) void ggemm_kernel(const float* __restrict__ featF,
                                                    const bf16* __restrict__ WihB,
                                                    const float* __restrict__ biasS,
                                                    bf16* __restrict__ Gp) {
  __shared__ __align__(16) bf16 Gs[32][520];    // 33.3KB, pad 520
  const int lane = threadIdx.x & 63, wave = threadIdx.x >> 6;
  const int l15 = lane & 15, quad = lane >> 4;
  const int nb = blockIdx.x * 64;
  const int tid = threadIdx.x;

  s16x8 Bx[4][4];
#pragma unroll
  for (int nt = 0; nt < 4; ++nt) {
    int arow = nb + nt * 16 + l15; if (arow >= NN) arow = NN - 1;
#pragma unroll
    for (int kt = 0; kt < 4; ++kt)
      Bx[nt][kt] = ldfrag_f32(featF + (size_t)arow * HIDD + kt * 32 + quad * 8);
  }

#pragma unroll
  for (int pass = 0; pass < 2; ++pass) {
    for (int hg = wave * 8; hg < wave * 8 + 8; ++hg) {
      const int wr = (l15 & 3) * HIDD + hg * 4 + (l15 >> 2);
      s16x8 Aw[4];
#pragma unroll
      for (int kt = 0; kt < 4; ++kt)
        Aw[kt] = ldfrag(WihB + (size_t)wr * HIDD + kt * 32 + quad * 8);
      const int hcol = hg * 4 + quad;
      // packed layout base: w=hcol>>3, quad_r=hcol&3, gt=(hcol>>2)&1
      const int gbase = (hcol >> 3) * 32 + (hcol & 3) * 8 + ((hcol >> 2) & 1) * 4;
      float b0 = biasS[0 * HIDD + hcol], b1 = biasS[1 * HIDD + hcol];
      float b2 = biasS[2 * HIDD + hcol], b3 = biasS[3 * HIDD + hcol];
#pragma unroll
      for (int nt2 = 0; nt2 < 2; ++nt2) {
        const int nt = pass * 2 + nt2;
        f32x4 acc = {0.f, 0.f, 0.f, 0.f};
#pragma unroll
        for (int kt = 0; kt < 4; ++kt)
          acc = MFMA16(Aw[kt], Bx[nt][kt], acc);
        unsigned u0 = packbf2(acc[0] + b0, acc[1] + b1);
        unsigned u1 = packbf2(acc[2] + b2, acc[3] + b3);
        *(uint2*)(&Gs[nt2 * 16 + l15][gbase]) = make_uint2(u0, u1);
      }
    }
    __syncthreads();
    // coalesced write-out: 2048 chunks of 8 els; consecutive lanes contiguous
    for (int e = tid; e < 2048; e += 256) {
      const int r = e >> 6, off = (e & 63) * 8;
      const int node = nb + pass * 32 + r;
      if (node < NN)
        *(s16x8*)(Gp + (size_t)node * 512 + off) = *(const s16x8*)(&Gs[r][off]);
    }
    __syncthreads();
  }
}

// ---------------- LSTM recurrence + fused SAGE epilogue ----------------
// 1024 thr / 16 waves / 64 nodes. Recurrence = R13 structure; x-gates now
// gathered as ONE 16B load per node per thread (packed G'' layout).
__global__ __launch_bounds__(1024, 4) void lstm_kernel(const bf16* __restrict__ Gp,
                                                       const bf16* __restrict__ WhhB,
                                                       const float* __restrict__ featF,
                                                       const bf16* __restrict__ WsT,
                                                       const bf16* __restrict__ WnT,
                                                       const float* __restrict__ b_sage,
                                                       const int* __restrict__ nbr_idx,
                                                       const int* __restrict__ deg,
                                                       const int* __restrict__ perm,
                                                       bf16* __restrict__ h1n) {
  __shared__ __align__(16) bf16 Hs[2][64 * 128];  // 32KB: h dbuf, oct-xor swizzled
  __shared__ int nbr_s[16 * 64];                  // [t][row]
  __shared__ int nodes_s[64];
  __shared__ int degs_s[64];

  const int tid = threadIdx.x;
  const int lane = tid & 63, w = tid >> 6;        // w = hcol-block 0..15
  const int l15 = lane & 15, quad = lane >> 4;
  const int base = blockIdx.x * 64;

  if (tid < 64) {
    const int gi = base + tid;
    const int nd = (gi < NN) ? perm[gi] : -1;
    nodes_s[tid] = nd;
    degs_s[tid] = (nd >= 0) ? deg[nd] : 0;
  }
  __syncthreads();
  {
    const int row = tid & 63, t = tid >> 6;       // exactly one entry per thread
    const int nd = nodes_s[row];
    nbr_s[t * 64 + row] = (nd >= 0) ? nbr_idx[nd * MAXD + t] : 0;
  }

  // pinned Whh packed frags: vrow v=l15 -> Whh row (v&3)*128 + w*8 + gt*4 + (v>>2)
  s16x8 Bh[2][4];
#pragma unroll
  for (int gt = 0; gt < 2; ++gt) {
    const int wr = (l15 & 3) * HIDD + w * 8 + gt * 4 + (l15 >> 2);
#pragma unroll
    for (int kt = 0; kt < 4; ++kt) {
      Bh[gt][kt] = ldfrag(WhhB + (size_t)wr * HIDD + kt * 32 + quad * 8);
      asm volatile("" : "+v"(Bh[gt][kt]));
    }
  }

  __syncthreads();                                // nbr_s visible
  const int maxdeg = degs_s[0];                   // descending sort -> block max

  int mydeg[4];
#pragma unroll
  for (int nt = 0; nt < 4; ++nt) mydeg[nt] = degs_s[nt * 16 + l15];

  // per-thread packed G'' element offset (16B = both gt chunks)
  const int gofs = w * 32 + quad * 8;

  float cst[2][4] = {{0.f, 0.f, 0.f, 0.f}, {0.f, 0.f, 0.f, 0.f}};
  float hprev[2][4] = {{0.f, 0.f, 0.f, 0.f}, {0.f, 0.f, 0.f, 0.f}};

  for (int t = 0; t < maxdeg; ++t) {
    const int cur = t & 1, nxt = cur ^ 1;

    // gather x-gates: ONE 16B load per node (was 2x8B)
    uint2 gx[2][4];
#pragma unroll
    for (int nt = 0; nt < 4; ++nt) {
      const int nb1 = nbr_s[t * 64 + nt * 16 + l15];
      const uint4 g4 = *(const uint4*)(Gp + (size_t)nb1 * 512 + gofs);
      gx[0][nt] = make_uint2(g4.x, g4.y);
      gx[1][nt] = make_uint2(g4.z, g4.w);
    }

    f32x4 acc[2][4];
#pragma unroll
    for (int gt = 0; gt < 2; ++gt)
#pragma unroll
      for (int nt = 0; nt < 4; ++nt) acc[gt][nt] = (f32x4){0.f, 0.f, 0.f, 0.f};

    // h-part: gates += Whh_packed @ h^T  (skip at t=0: h0 = 0)
    if (t > 0) {
      __builtin_amdgcn_s_setprio(1);
#pragma unroll
      for (int kt = 0; kt < 4; ++kt) {
#pragma unroll
        for (int nt = 0; nt < 4; ++nt) {
          const int row = nt * 16 + l15;
          const s16x8 ah = ldfrag(Hs[cur] + row * 128 + (((kt * 4 + quad) ^ l15) * 8));
#pragma unroll
          for (int gt = 0; gt < 2; ++gt)
            acc[gt][nt] = MFMA16(Bh[gt][kt], ah, acc[gt][nt]);
        }
      }
      __builtin_amdgcn_s_setprio(0);
    }

    // elementwise cell: lane's f32x4 = all 4 gates of one cell
#pragma unroll
    for (int gt = 0; gt < 2; ++gt) {
      const int col = w * 8 + gt * 4 + quad;
#pragma unroll
      for (int nt = 0; nt < 4; ++nt) {
        const int row = nt * 16 + l15;
        const uint2 g = gx[gt][nt];
        const float g_i = acc[gt][nt][0] + lo2f(g.x);
        const float g_f = acc[gt][nt][1] + hi2f(g.x);
        const float g_g = acc[gt][nt][2] + lo2f(g.y);
        const float g_o = acc[gt][nt][3] + hi2f(g.y);
        const float iv = sigf(g_i), fv = sigf(g_f);
        const float gv = tanhf_(g_g), ov = sigf(g_o);
        const float cn = fv * cst[gt][nt] + iv * gv;
        const float hn_new = ov * tanhf_(cn);
        const bool act = (t < mydeg[nt]);
        if (act) cst[gt][nt] = cn;
        const float hn = act ? hn_new : hprev[gt][nt];
        hprev[gt][nt] = hn;
        Hs[nxt][row * 128 + ((w ^ (row & 15)) * 8) + (col & 7)] = f2bf(hn);
      }
    }
    lgkm_barrier();   // single barrier: dbuf writes visible, reads done
  }

  // ---- fused SAGE epilogue: h1n = relu(feat@Ws + hT@Wn + b) * rsqrt(deg) ----
  const bf16* Hf = Hs[maxdeg & 1];
  {
    const int rq = w & 3, cp = w >> 2;
    const int rowA = rq * 16 + l15;               // A-frag row (m index)
    const int ndA = nodes_s[rowA];
    const int ndA2 = (ndA >= 0) ? ndA : 0;        // garbage rows never written
    s16x8 Fa[4], Ha[4];
#pragma unroll
    for (int kt = 0; kt < 4; ++kt) {
      Fa[kt] = ldfrag_f32(featF + (size_t)ndA2 * HIDD + kt * 32 + quad * 8);
      Ha[kt] = ldfrag(Hf + rowA * 128 + (((kt * 4 + quad) ^ l15) * 8));
    }
    int ndC[4]; float nrmC[4];
#pragma unroll
    for (int r = 0; r < 4; ++r) {
      const int rowC = rq * 16 + quad * 4 + r;
      ndC[r] = nodes_s[rowC];
      const int dd = degs_s[rowC];
      nrmC[r] = rsqrtf((float)((dd > 0) ? dd : 1));
    }
#pragma unroll
    for (int cc = 0; cc < 2; ++cc) {
      const int col = (cp * 2 + cc) * 16 + l15;
      f32x4 acc = {0.f, 0.f, 0.f, 0.f};
#pragma unroll
      for (int kt = 0; kt < 4; ++kt) {
        acc = MFMA16(Fa[kt], ldfrag(WsT + col * HIDD + kt * 32 + quad * 8), acc);
        acc = MFMA16(Ha[kt], ldfrag(WnT + col * HIDD + kt * 32 + quad * 8), acc);
      }
      const float bb = b_sage[col];
#pragma unroll
      for (int r = 0; r < 4; ++r)
        if (ndC[r] >= 0)
          h1n[(size_t)ndC[r] * HIDD + col] = f2bf(fmaxf(acc[r] + bb, 0.f) * nrmC[r]);
    }
  }
}

// ------- FUSED: agg gather -> gc GEMM -> GRU -> per-graph pool partial -------
__global__ __launch_bounds__(256) void aggru_kernel(const bf16* __restrict__ h1n,
                                                    const int* __restrict__ nbr_idx,
                                                    const int* __restrict__ deg,
                                                    const int* __restrict__ gids,
                                                    const bf16* __restrict__ WgT,
                                                    const float* __restrict__ b_gc,
                                                    const bf16* __restrict__ WgruB,
                                                    const float* __restrict__ bih,
                                                    const float* __restrict__ bhh,
                                                    float* __restrict__ psums,
                                                    float* __restrict__ pcnts) {
  __shared__ __align__(16) bf16 Ag[64 * 136];     // aggregated rows, padded pitch
  __shared__ __align__(16) bf16 H2[64 * 136];     // h2 tile, padded pitch
  __shared__ int nbrL[64 * 16];                   // [node][t] nbr lists
  __shared__ float psl[2 * GRUH];
  __shared__ float pcl[2];
  const int tid = threadIdx.x;
  const int lane = tid & 63, wave = tid >> 6;
  const int l15 = lane & 15, quad = lane >> 4;
  const int nbb = blockIdx.x * 64;
  const int nb = nbb + wave * 16;

  if (tid < 2 * GRUH) psl[tid] = 0.f;
  if (tid < 2) pcl[tid] = 0.f;

  // stage nbr lists (contiguous copy)
  for (int e = tid; e < 64 * 16; e += 256) {
    const int node = nbb + (e >> 4);
    nbrL[e] = (node < NN) ? nbr_idx[node * MAXD + (e & 15)] : 0;
  }
  __syncthreads();

  // phase A: node-parallel gather. thread -> (node = tid>>2, cols (tid&3)*32..+31)
  {
    const int myn = tid >> 2;
    const int node = nbb + myn;
    const int seg = (tid & 3) * 32;
    const int d = (node < NN) ? deg[node] : 0;
    float accv[32];
#pragma unroll
    for (int k = 0; k < 32; ++k) accv[k] = 0.f;
#pragma unroll 2
    for (int j = 0; j < d; ++j) {
      const int nbr = nbrL[myn * 16 + j];
      const bf16* rp = h1n + (size_t)nbr * HIDD + seg;
#pragma unroll
      for (int f = 0; f < 4; ++f) {
        union { s16x8 v; unsigned u[4]; } t_;
        t_.v = ldfrag(rp + f * 8);
#pragma unroll
        for (int p = 0; p < 4; ++p) {
          accv[f * 8 + 2 * p]     += lo2f(t_.u[p]);
          accv[f * 8 + 2 * p + 1] += hi2f(t_.u[p]);
        }
      }
    }
    const float nm = (d > 0) ? rsqrtf((float)d) : 0.f;
#pragma unroll
    for (int f = 0; f < 4; ++f) {
      union { s16x8 v; bf16 h[8]; } o;
#pragma unroll
      for (int k = 0; k < 8; ++k) o.h[k] = f2bf(accv[f * 8 + k] * nm);
      *(s16x8*)(Ag + myn * 136 + seg + f * 8) = o.v;
    }
  }
  __syncthreads();

  // phase B1: gc GEMM from Ag; h2 = relu(.) -> H2
  s16x8 A[4];
#pragma unroll
  for (int kt = 0; kt < 4; ++kt)
    A[kt] = ldfrag(Ag + (wave * 16 + l15) * 136 + kt * 32 + quad * 8);
  for (int ct = 0; ct < 8; ++ct) {
    const int col = ct * 16 + l15;
    f32x4 acc = {0.f, 0.f, 0.f, 0.f};
#pragma unroll
    for (int kt = 0; kt < 4; ++kt)
      acc = MFMA16(A[kt], ldfrag(WgT + col * HIDD + kt * 32 + quad * 8), acc);
    const float bb = b_gc[col];
#pragma unroll
    for (int r = 0; r < 4; ++r)
      H2[(wave * 16 + quad * 4 + r) * 136 + col] = f2bf(fmaxf(acc[r] + bb, 0.f));
  }
  __syncthreads();

  // phase B2: gru GEMM over rows wave*16 + l15
  s16x8 A2[4];
#pragma unroll
  for (int kt = 0; kt < 4; ++kt)
    A2[kt] = ldfrag(H2 + (wave * 16 + l15) * 136 + kt * 32 + quad * 8);
  f32x4 acc[6];
#pragma unroll
  for (int ct = 0; ct < 6; ++ct) {
    f32x4 a = {0.f, 0.f, 0.f, 0.f};
#pragma unroll
    for (int kt = 0; kt < 4; ++kt)
      a = MFMA16(A2[kt], ldfrag(WgruB + (ct * 16 + l15) * HIDD + kt * 32 + quad * 8), a);
    acc[ct] = a;
  }

  // phase C: gru activation + per-graph accumulate (block spans <=2 graphs)
  const int g0 = gids[nbb];
  int mynode[4], mygs[4];
#pragma unroll
  for (int r = 0; r < 4; ++r) {
    const int nd = nb + quad * 4 + r;
    mynode[r] = nd;
    mygs[r] = (nd < NN) ? (gids[nd] - g0) : 0;
  }
#pragma unroll
  for (int u = 0; u < 2; ++u) {
    const int cu = 16 * u + l15;
    const float br = bih[cu] + bhh[cu];
    const float bz = bih[32 + cu] + bhh[32 + cu];
    const float bni = bih[64 + cu];
    const float bnh = bhh[64 + cu];
#pragma unroll
    for (int r = 0; r < 4; ++r) {
      if (mynode[r] < NN) {
        const float rv = sigf(acc[u][r] + br);
        const float zv = sigf(acc[2 + u][r] + bz);
        const float nv = tanhf_(acc[4 + u][r] + bni + rv * bnh);
        const float v = (1.f - zv) * nv;
        atomicAdd(&psl[mygs[r] * GRUH + cu], v);
        if (u == 0 && l15 == 0) atomicAdd(&pcl[mygs[r]], 1.f);
      }
    }
  }
  __syncthreads();
  if (tid < 2 * GRUH) {
    const int s = tid >> 5, c = tid & 31;
    const float vv = psl[tid];
    if (vv != 0.f && g0 + s < NGRAPH) atomicAdd(&psums[(g0 + s) * GRUH + c], vv);
  }
  if (tid < 2) {
    if (pcl[tid] != 0.f && g0 + tid < NGRAPH) atomicAdd(&pcnts[g0 + tid], pcl[tid]);
  }
}

// ------- final: per-graph mean + classifier -------
__global__ __launch_bounds__(256) void pool_final_kernel(const float* __restrict__ sums,
                                                         const float* __restrict__ cnts,
                                                         const float* __restrict__ Wcls,
                                                         const float* __restrict__ bcls,
                                                         float* __restrict__ out) {
  const int idx = blockIdx.x * blockDim.x + threadIdx.x;
  if (idx >= NGRAPH * NCLSS) return;
  const int g = idx / NCLSS, k = idx % NCLSS;
  const float inv = 1.0f / cnts[g];
  float acc = bcls[k];
#pragma unroll
  for (int cc = 0; cc < GRUH; ++cc)
    acc += sums[g * GRUH + cc] * inv * Wcls[cc * NCLSS + k];
  out[idx] = acc;
}

extern "C" void kernel_launch(void* const* d_in, const int* in_sizes, int n_in,
                              void* d_out, int out_size, void* d_ws, size_t ws_size,
                              hipStream_t stream) {
  const float* feature  = (const float*)d_in[0];
  const int*   nbr_idx  = (const int*)d_in[1];
  const int*   deg      = (const int*)d_in[2];
  const int*   gids     = (const int*)d_in[3];
  const float* lstm_Wih = (const float*)d_in[4];
  const float* lstm_Whh = (const float*)d_in[5];
  const float* lstm_bih = (const float*)d_in[6];
  const float* lstm_bhh = (const float*)d_in[7];
  const float* W_self   = (const float*)d_in[8];
  const float* W_neigh  = (const float*)d_in[9];
  const float* b_sage   = (const float*)d_in[10];
  const float* W_gc     = (const float*)d_in[11];
  const float* b_gc     = (const float*)d_in[12];
  const float* Wih_gru  = (const float*)d_in[13];
  const float* bih_gru  = (const float*)d_in[14];
  const float* bhh_gru  = (const float*)d_in[15];
  const float* W_cls    = (const float*)d_in[16];
  const float* b_cls    = (const float*)d_in[17];

  // workspace: peak 64.8 MB (within the 65.4 MB proven bound).
  // h1n at 0 (lstm-epilogue out, aggru in); Gp at 12.8M (dead after lstm).
  char* ws = (char*)d_ws;
  bf16*  h1nB  = (bf16*)(ws + 0);           // [NN,128] 12.8MB
  bf16*  Gp    = (bf16*)(ws + 12800000);    // [NN,512] 51.2MB (dead after lstm)
  const size_t wo = 64000000;
  bf16*  WihB  = (bf16*)(ws + wo);
  bf16*  WhhB  = (bf16*)(ws + wo + 131072);
  bf16*  WsT   = (bf16*)(ws + wo + 262144);
  bf16*  WnT   = (bf16*)(ws + wo + 294912);
  bf16*  WgT   = (bf16*)(ws + wo + 327680);
  bf16*  WgruB = (bf16*)(ws + wo + 360448);
  float* biasS = (float*)(ws + wo + 385024);
  int*   perm  = (int*)(ws + 64500000);
  int*   hist  = (int*)(ws + 64800000);     // [17] + resv [17]
  int*   resv  = hist + 17;
  float* psums = (float*)(ws + 64801216);   // [50][32] + pcnts [50]
  float* pcnts = psums + NGRAPH * GRUH;

  prep_kernel<<<754, 256, 0, stream>>>(lstm_Wih, lstm_Whh, lstm_bih, lstm_bhh,
                                       W_self, W_neigh, W_gc, Wih_gru,
                                       WihB, WhhB, WsT, WnT, WgT, WgruB, biasS,
                                       hist, psums);
  hist_kernel<<<196, 256, 0, stream>>>(deg, hist);
  scatter_kernel<<<196, 256, 0, stream>>>(deg, hist, resv, perm);
  ggemm_kernel<<<782, 256, 0, stream>>>(feature, WihB, biasS, Gp);
  lstm_kernel<<<782, 1024, 0, stream>>>(Gp, WhhB, feature, WsT, WnT, b_sage,
                                        nbr_idx, deg, perm, h1nB);
  aggru_kernel<<<782, 256, 0, stream>>>(h1nB, nbr_idx, deg, gids, WgT, b_gc,
                                        WgruB, bih_gru, bhh_gru, psums, pcnts);
  pool_final_kernel<<<2, 256, 0, stream>>>(psums, pcnts, W_cls, b_cls, (float*)d_out);
}